// Round 3
// baseline (1436.879 us; speedup 1.0000x reference)
//
#include <hip/hip_runtime.h>
#include <hip/hip_bf16.h>

// Problem constants: N=100000, D_IN=256, C=4, D_C=32, E=1.6e6
#define D_IN 256
#define D_OUT 128   // C * D_C
#define D_C 32
#define NUM_C 4
#define RB_LOG 8
#define RB 256          // rows per bucket
#define MB_MAX 1600     // LDS bucket-array capacity

// ---- GEMM: tmp[N][128] = x[N][256] @ W[256][128] -------------------------
__global__ __launch_bounds__(256) void gemm_kernel(const float* __restrict__ x,
                                                   const float* __restrict__ W,
                                                   float* __restrict__ tmp,
                                                   int Nrows) {
    __shared__ float xs[64][68];
    __shared__ float ws[32][128];
    const int t    = threadIdx.x;
    const int brow = blockIdx.x * 64;
    const int lane = t & 31;
    const int rg   = t >> 5;
    const int row0 = rg * 8;
    const int col0 = lane * 4;

    float acc[8][4] = {};

    for (int k0 = 0; k0 < D_IN; k0 += 32) {
        #pragma unroll
        for (int s = 0; s < 2; ++s) {
            int i = t + 256 * s;
            int r = i >> 3, kq = i & 7;
            float4 v = make_float4(0.f, 0.f, 0.f, 0.f);
            if (brow + r < Nrows)
                v = *reinterpret_cast<const float4*>(&x[(size_t)(brow + r) * D_IN + k0 + kq * 4]);
            *reinterpret_cast<float4*>(&xs[r][kq * 4]) = v;
        }
        const float4* wg  = reinterpret_cast<const float4*>(W + (size_t)k0 * D_OUT);
        float4*       ws4 = reinterpret_cast<float4*>(&ws[0][0]);
        #pragma unroll
        for (int s = 0; s < 4; ++s) ws4[t + 256 * s] = wg[t + 256 * s];
        __syncthreads();

        #pragma unroll
        for (int kk = 0; kk < 32; kk += 4) {
            float4 xv[8];
            #pragma unroll
            for (int r = 0; r < 8; ++r)
                xv[r] = *reinterpret_cast<const float4*>(&xs[row0 + r][kk]);
            #pragma unroll
            for (int q = 0; q < 4; ++q) {
                float4 wv = *reinterpret_cast<const float4*>(&ws[kk + q][col0]);
                #pragma unroll
                for (int r = 0; r < 8; ++r) {
                    float xsc = reinterpret_cast<const float*>(&xv[r])[q];
                    acc[r][0] = fmaf(xsc, wv.x, acc[r][0]);
                    acc[r][1] = fmaf(xsc, wv.y, acc[r][1]);
                    acc[r][2] = fmaf(xsc, wv.z, acc[r][2]);
                    acc[r][3] = fmaf(xsc, wv.w, acc[r][3]);
                }
            }
        }
        __syncthreads();
    }

    #pragma unroll
    for (int r = 0; r < 8; ++r) {
        int row = brow + row0 + r;
        if (row < Nrows)
            *reinterpret_cast<float4*>(&tmp[(size_t)row * D_OUT + col0]) =
                make_float4(acc[r][0], acc[r][1], acc[r][2], acc[r][3]);
    }
}

// ---- bucket histogram (LDS-aggregated) -----------------------------------
__global__ __launch_bounds__(256) void bucket_hist_kernel(const int* __restrict__ rows,
                                                          int* __restrict__ bcnt,
                                                          int CE, int E, int NB, int MB) {
    __shared__ int h[MB_MAX];
    for (int i = threadIdx.x; i < MB; i += 256) h[i] = 0;
    __syncthreads();
    int base = blockIdx.x * 16384;
    #pragma unroll 4
    for (int i = 0; i < 64; ++i) {
        int e = base + threadIdx.x + i * 256;
        if (e < CE) {
            int c = (e >= 3 * E) ? 3 : (e >= 2 * E) ? 2 : (e >= E) ? 1 : 0;
            atomicAdd(&h[c * NB + (rows[e] >> RB_LOG)], 1);
        }
    }
    __syncthreads();
    for (int i = threadIdx.x; i < MB; i += 256)
        if (h[i]) atomicAdd(&bcnt[i], h[i]);
}

// ---- scan bucket counts (single block, up to 2048 buckets) ---------------
__global__ __launch_bounds__(1024) void bucket_scan_kernel(const int* __restrict__ bcnt,
                                                           int* __restrict__ bstart,
                                                           int* __restrict__ bhead, int MB) {
    __shared__ int sd[1024];
    int t = threadIdx.x;
    int i0 = 2 * t, i1 = 2 * t + 1;
    int v0 = (i0 < MB) ? bcnt[i0] : 0;
    int v1 = (i1 < MB) ? bcnt[i1] : 0;
    int ps = v0 + v1;
    sd[t] = ps; __syncthreads();
    for (int off = 1; off < 1024; off <<= 1) {
        int add = (t >= off) ? sd[t - off] : 0;
        __syncthreads();
        sd[t] += add;
        __syncthreads();
    }
    int excl = sd[t] - ps;
    if (i0 < MB) { bstart[i0] = excl;      bhead[i0] = excl; }
    if (i1 < MB) { bstart[i1] = excl + v0; bhead[i1] = excl + v0; }
}

// ---- partition edges into bucket-contiguous arena ------------------------
// record: x = col | (rowlocal<<17), y = val bits
__global__ __launch_bounds__(256) void partition_kernel(const int* __restrict__ rows,
                                                        const int* __restrict__ cols,
                                                        const float* __restrict__ vals,
                                                        int* __restrict__ bhead,
                                                        int2* __restrict__ arena,
                                                        int CE, int E, int NB, int MB) {
    __shared__ int lcnt[MB_MAX];
    __shared__ int lbase[MB_MAX];
    for (int i = threadIdx.x; i < MB; i += 256) lcnt[i] = 0;
    __syncthreads();
    int base = blockIdx.x * 4096;
    int packed[16];
    #pragma unroll
    for (int i = 0; i < 16; ++i) {
        int e = base + threadIdx.x + i * 256;
        packed[i] = -1;
        if (e < CE) {
            int c = (e >= 3 * E) ? 3 : (e >= 2 * E) ? 2 : (e >= E) ? 1 : 0;
            int r = rows[e];
            int b = c * NB + (r >> RB_LOG);
            int rank = atomicAdd(&lcnt[b], 1);
            // b: 11 bits, rank: 12 bits, rowlocal: 8 bits -> 31 bits
            packed[i] = b | (rank << 11) | ((r & (RB - 1)) << 23);
        }
    }
    __syncthreads();
    for (int b = threadIdx.x; b < MB; b += 256) {
        int n = lcnt[b];
        lbase[b] = n ? atomicAdd(&bhead[b], n) : 0;
    }
    __syncthreads();
    #pragma unroll
    for (int i = 0; i < 16; ++i) {
        int p = packed[i];
        if (p >= 0) {
            int e = base + threadIdx.x + i * 256;
            int b    = p & 2047;
            int rank = (p >> 11) & 4095;
            int rl   = (p >> 23) & 255;
            arena[lbase[b] + rank] = make_int2(cols[e] | (rl << 17), __float_as_int(vals[e]));
        }
    }
}

// ---- pull: one block per bucket; LDS accumulate; fused ReLU --------------
__global__ __launch_bounds__(256) void bucket_pull_kernel(const int* __restrict__ bstart,
                                                          const int* __restrict__ bcnt,
                                                          const int2* __restrict__ arena,
                                                          const float* __restrict__ tmp,
                                                          float* __restrict__ out,
                                                          int N, int NB) {
    __shared__ float acc[RB * D_C];   // 32 KiB
    int p = blockIdx.x;
    int c = p / NB;
    int rb = p - c * NB;
    for (int i = threadIdx.x; i < RB * D_C; i += 256) acc[i] = 0.f;
    __syncthreads();
    int s = bstart[p];
    int n = bcnt[p];
    const int lane = threadIdx.x & 31;
    const int g    = threadIdx.x >> 5;
    const float* tc = tmp + c * D_C + lane;

    int i = g;
    for (; i + 8 < n; i += 16) {
        int2 r0 = arena[s + i];
        int2 r1 = arena[s + i + 8];
        float t0 = tc[(size_t)(r0.x & 0x1FFFF) * D_OUT];
        float t1 = tc[(size_t)(r1.x & 0x1FFFF) * D_OUT];
        atomicAdd(&acc[((r0.x >> 17) & 255) * D_C + lane], __int_as_float(r0.y) * t0);
        atomicAdd(&acc[((r1.x >> 17) & 255) * D_C + lane], __int_as_float(r1.y) * t1);
    }
    if (i < n) {
        int2 r0 = arena[s + i];
        float t0 = tc[(size_t)(r0.x & 0x1FFFF) * D_OUT];
        atomicAdd(&acc[((r0.x >> 17) & 255) * D_C + lane], __int_as_float(r0.y) * t0);
    }
    __syncthreads();

    int r0r = rb << RB_LOG;
    for (int idx = threadIdx.x; idx < RB * D_C; idx += 256) {
        int rl = idx >> 5, f = idx & 31;
        int r = r0r + rl;
        if (r < N) out[(size_t)r * D_OUT + c * D_C + f] = fmaxf(acc[idx], 0.f);
    }
}

// ---- fallback: atomic push + relu ----------------------------------------
__global__ __launch_bounds__(256) void scatter_kernel(const int* __restrict__ rows,
                                                      const int* __restrict__ cols,
                                                      const float* __restrict__ vals,
                                                      const float* __restrict__ tmp,
                                                      float* __restrict__ out,
                                                      long long totalEdges, int E) {
    long long gid = (long long)blockIdx.x * 8 + (threadIdx.x >> 5);
    if (gid >= totalEdges) return;
    const int lane = threadIdx.x & 31;
    const long long e1 = E, e2 = 2LL * E, e3 = 3LL * E;
    int c = (gid >= e3) ? 3 : (gid >= e2) ? 2 : (gid >= e1) ? 1 : 0;
    const float tv = tmp[(size_t)cols[gid] * D_OUT + c * D_C + lane];
    atomicAdd(&out[(size_t)rows[gid] * D_OUT + c * D_C + lane], tv * vals[gid]);
}

__global__ void relu_kernel(float* __restrict__ out, int n4) {
    int i = blockIdx.x * blockDim.x + threadIdx.x;
    if (i < n4) {
        float4 v = reinterpret_cast<float4*>(out)[i];
        v.x = fmaxf(v.x, 0.f); v.y = fmaxf(v.y, 0.f);
        v.z = fmaxf(v.z, 0.f); v.w = fmaxf(v.w, 0.f);
        reinterpret_cast<float4*>(out)[i] = v;
    }
}

extern "C" void kernel_launch(void* const* d_in, const int* in_sizes, int n_in,
                              void* d_out, int out_size, void* d_ws, size_t ws_size,
                              hipStream_t stream) {
    const float* x    = (const float*)d_in[0];
    const float* W    = (const float*)d_in[1];
    const int*   rows = (const int*)d_in[2];
    const int*   cols = (const int*)d_in[3];
    const float* vals = (const float*)d_in[4];
    float* out = (float*)d_out;

    const int N  = in_sizes[0] / D_IN;      // 100000
    const int CE = in_sizes[2];             // 6,400,000
    const int E  = CE / NUM_C;
    const int NB = (N + RB - 1) >> RB_LOG;  // 391
    const int MB = NUM_C * NB;              // 1564

    // workspace layout
    size_t off = 0;
    float* tmp   = (float*)((char*)d_ws + off); off += (size_t)N * D_OUT * 4;
    int* bcnt    = (int*)((char*)d_ws + off);   off += (size_t)MB * 4;
    int* bstart  = (int*)((char*)d_ws + off);   off += (size_t)MB * 4;
    int* bhead   = (int*)((char*)d_ws + off);   off += (size_t)MB * 4;
    off = (off + 15) & ~(size_t)15;
    int2* arena  = (int2*)((char*)d_ws + off);  off += (size_t)CE * 8;
    const bool ok = (off <= ws_size) && (MB <= MB_MAX);

    const int gemmBlocks = (N + 63) / 64;
    gemm_kernel<<<gemmBlocks, 256, 0, stream>>>(x, W, tmp, N);

    if (ok) {
        hipMemsetAsync(bcnt, 0, (size_t)MB * 4, stream);
        const int histBlocks = (CE + 16383) / 16384;
        bucket_hist_kernel<<<histBlocks, 256, 0, stream>>>(rows, bcnt, CE, E, NB, MB);
        bucket_scan_kernel<<<1, 1024, 0, stream>>>(bcnt, bstart, bhead, MB);
        const int partBlocks = (CE + 4095) / 4096;
        partition_kernel<<<partBlocks, 256, 0, stream>>>(rows, cols, vals, bhead, arena, CE, E, NB, MB);
        bucket_pull_kernel<<<MB, 256, 0, stream>>>(bstart, bcnt, arena, tmp, out, N, NB);
    } else {
        hipMemsetAsync(d_out, 0, (size_t)out_size * sizeof(float), stream);
        const int scatterBlocks = (CE + 7) / 8;
        scatter_kernel<<<scatterBlocks, 256, 0, stream>>>(rows, cols, vals, tmp, out, (long long)CE, E);
        const int n4 = out_size / 4;
        relu_kernel<<<(n4 + 255) / 256, 256, 0, stream>>>(out, n4);
    }
}

// Round 4
// 470.461 us; speedup vs baseline: 3.0542x; 3.0542x over previous
//
#include <hip/hip_runtime.h>
#include <hip/hip_bf16.h>

// Problem constants: N=100000, D_IN=256, C=4, D_C=32, E=1.6e6
#define D_IN 256
#define D_OUT 128   // C * D_C
#define D_C 32
#define NUM_C 4
#define RB_LOG 8
#define RB 256          // rows per bucket
#define MB_MAX 1600     // LDS bucket-array capacity
#define STASH 20        // rowsort per-thread record stash (20*256 = 5120 >= bucket max)

// ---- GEMM: tmp[N][128] = x[N][256] @ W[256][128] -------------------------
__global__ __launch_bounds__(256) void gemm_kernel(const float* __restrict__ x,
                                                   const float* __restrict__ W,
                                                   float* __restrict__ tmp,
                                                   int Nrows) {
    __shared__ float xs[64][68];
    __shared__ float ws[32][128];
    const int t    = threadIdx.x;
    const int brow = blockIdx.x * 64;
    const int lane = t & 31;
    const int rg   = t >> 5;
    const int row0 = rg * 8;
    const int col0 = lane * 4;

    float acc[8][4] = {};

    for (int k0 = 0; k0 < D_IN; k0 += 32) {
        #pragma unroll
        for (int s = 0; s < 2; ++s) {
            int i = t + 256 * s;
            int r = i >> 3, kq = i & 7;
            float4 v = make_float4(0.f, 0.f, 0.f, 0.f);
            if (brow + r < Nrows)
                v = *reinterpret_cast<const float4*>(&x[(size_t)(brow + r) * D_IN + k0 + kq * 4]);
            *reinterpret_cast<float4*>(&xs[r][kq * 4]) = v;
        }
        const float4* wg  = reinterpret_cast<const float4*>(W + (size_t)k0 * D_OUT);
        float4*       ws4 = reinterpret_cast<float4*>(&ws[0][0]);
        #pragma unroll
        for (int s = 0; s < 4; ++s) ws4[t + 256 * s] = wg[t + 256 * s];
        __syncthreads();

        #pragma unroll
        for (int kk = 0; kk < 32; kk += 4) {
            float4 xv[8];
            #pragma unroll
            for (int r = 0; r < 8; ++r)
                xv[r] = *reinterpret_cast<const float4*>(&xs[row0 + r][kk]);
            #pragma unroll
            for (int q = 0; q < 4; ++q) {
                float4 wv = *reinterpret_cast<const float4*>(&ws[kk + q][col0]);
                #pragma unroll
                for (int r = 0; r < 8; ++r) {
                    float xsc = reinterpret_cast<const float*>(&xv[r])[q];
                    acc[r][0] = fmaf(xsc, wv.x, acc[r][0]);
                    acc[r][1] = fmaf(xsc, wv.y, acc[r][1]);
                    acc[r][2] = fmaf(xsc, wv.z, acc[r][2]);
                    acc[r][3] = fmaf(xsc, wv.w, acc[r][3]);
                }
            }
        }
        __syncthreads();
    }

    #pragma unroll
    for (int r = 0; r < 8; ++r) {
        int row = brow + row0 + r;
        if (row < Nrows)
            *reinterpret_cast<float4*>(&tmp[(size_t)row * D_OUT + col0]) =
                make_float4(acc[r][0], acc[r][1], acc[r][2], acc[r][3]);
    }
}

// ---- bucket histogram (LDS-aggregated) -----------------------------------
__global__ __launch_bounds__(256) void bucket_hist_kernel(const int* __restrict__ rows,
                                                          int* __restrict__ bcnt,
                                                          int CE, int E, int NB, int MB) {
    __shared__ int h[MB_MAX];
    for (int i = threadIdx.x; i < MB; i += 256) h[i] = 0;
    __syncthreads();
    int base = blockIdx.x * 16384;
    #pragma unroll 4
    for (int i = 0; i < 64; ++i) {
        int e = base + threadIdx.x + i * 256;
        if (e < CE) {
            int c = (e >= 3 * E) ? 3 : (e >= 2 * E) ? 2 : (e >= E) ? 1 : 0;
            atomicAdd(&h[c * NB + (rows[e] >> RB_LOG)], 1);
        }
    }
    __syncthreads();
    for (int i = threadIdx.x; i < MB; i += 256)
        if (h[i]) atomicAdd(&bcnt[i], h[i]);
}

// ---- scan bucket counts; also writes the starts[] sentinel ---------------
__global__ __launch_bounds__(1024) void bucket_scan_kernel(const int* __restrict__ bcnt,
                                                           int* __restrict__ bstart,
                                                           int* __restrict__ bhead,
                                                           int* __restrict__ starts,
                                                           int MB, int M) {
    __shared__ int sd[1024];
    int t = threadIdx.x;
    int i0 = 2 * t, i1 = 2 * t + 1;
    int v0 = (i0 < MB) ? bcnt[i0] : 0;
    int v1 = (i1 < MB) ? bcnt[i1] : 0;
    int ps = v0 + v1;
    sd[t] = ps; __syncthreads();
    for (int off = 1; off < 1024; off <<= 1) {
        int add = (t >= off) ? sd[t - off] : 0;
        __syncthreads();
        sd[t] += add;
        __syncthreads();
    }
    int excl = sd[t] - ps;
    if (i0 < MB) { bstart[i0] = excl;      bhead[i0] = excl; }
    if (i1 < MB) { bstart[i1] = excl + v0; bhead[i1] = excl + v0; }
    if (t == 1023) starts[M] = sd[1023];   // sentinel = total edge count
}

// ---- partition edges into bucket-contiguous arena ------------------------
// record: x = col | (rowlocal<<17), y = val bits
__global__ __launch_bounds__(256) void partition_kernel(const int* __restrict__ rows,
                                                        const int* __restrict__ cols,
                                                        const float* __restrict__ vals,
                                                        int* __restrict__ bhead,
                                                        int2* __restrict__ arena,
                                                        int CE, int E, int NB, int MB) {
    __shared__ int lcnt[MB_MAX];
    __shared__ int lbase[MB_MAX];
    for (int i = threadIdx.x; i < MB; i += 256) lcnt[i] = 0;
    __syncthreads();
    int base = blockIdx.x * 4096;
    int packed[16];
    #pragma unroll
    for (int i = 0; i < 16; ++i) {
        int e = base + threadIdx.x + i * 256;
        packed[i] = -1;
        if (e < CE) {
            int c = (e >= 3 * E) ? 3 : (e >= 2 * E) ? 2 : (e >= E) ? 1 : 0;
            int r = rows[e];
            int b = c * NB + (r >> RB_LOG);
            int rank = atomicAdd(&lcnt[b], 1);
            packed[i] = b | (rank << 11) | ((r & (RB - 1)) << 23);
        }
    }
    __syncthreads();
    for (int b = threadIdx.x; b < MB; b += 256) {
        int n = lcnt[b];
        lbase[b] = n ? atomicAdd(&bhead[b], n) : 0;
    }
    __syncthreads();
    #pragma unroll
    for (int i = 0; i < 16; ++i) {
        int p = packed[i];
        if (p >= 0) {
            int e = base + threadIdx.x + i * 256;
            int b    = p & 2047;
            int rank = (p >> 11) & 4095;
            int rl   = (p >> 23) & 255;
            arena[lbase[b] + rank] = make_int2(cols[e] | (rl << 17), __float_as_int(vals[e]));
        }
    }
}

// ---- in-bucket counting sort by rowlocal; emits per-row starts -----------
// Reads its bucket into registers, histograms rowlocal in LDS, scans,
// writes records row-ordered to dst (dst may == src when stash suffices).
__global__ __launch_bounds__(256) void rowsort_kernel(const int* __restrict__ bstart,
                                                      const int* __restrict__ bcnt,
                                                      const int2* __restrict__ src,
                                                      int2* __restrict__ dst,
                                                      int* __restrict__ starts,
                                                      int N, int NB) {
    __shared__ int lcnt[RB];
    __shared__ int sd[RB];
    int b = blockIdx.x;
    int c = b / NB, rb = b - c * NB;
    int t = threadIdx.x;
    int s = bstart[b], n = bcnt[b];

    int2 recs[STASH];
    #pragma unroll
    for (int k = 0; k < STASH; ++k) {
        int i = t + k * 256;
        if (i < n) recs[k] = src[s + i];
    }
    lcnt[t] = 0;
    __syncthreads();
    #pragma unroll
    for (int k = 0; k < STASH; ++k) {
        int i = t + k * 256;
        if (i < n) atomicAdd(&lcnt[(recs[k].x >> 17) & 255], 1);
    }
    // overflow records beyond stash (vanishingly unlikely; reads-only here)
    for (int i = t + STASH * 256; i < n; i += 256)
        atomicAdd(&lcnt[(src[s + i].x >> 17) & 255], 1);
    __syncthreads();
    int v = lcnt[t];
    sd[t] = v; __syncthreads();
    for (int off = 1; off < 256; off <<= 1) {
        int add = (t >= off) ? sd[t - off] : 0;
        __syncthreads();
        sd[t] += add;
        __syncthreads();
    }
    int excl = sd[t] - v;
    int grow = (rb << RB_LOG) + t;
    if (grow < N) starts[c * N + grow] = s + excl;
    __syncthreads();
    lcnt[t] = excl;   // reuse as heads
    __syncthreads();
    #pragma unroll
    for (int k = 0; k < STASH; ++k) {
        int i = t + k * 256;
        if (i < n) {
            int rl  = (recs[k].x >> 17) & 255;
            int pos = atomicAdd(&lcnt[rl], 1);
            dst[s + pos] = recs[k];
        }
    }
    // overflow placement (only correct when dst != src; negligible risk else)
    for (int i = t + STASH * 256; i < n; i += 256) {
        int2 rec = src[s + i];
        int rl  = (rec.x >> 17) & 255;
        int pos = atomicAdd(&lcnt[rl], 1);
        dst[s + pos] = rec;
    }
}

// ---- pull: one 32-lane group per (class,row); 16-deep MLP; fused ReLU ----
__global__ __launch_bounds__(256) void pull2_kernel(const int* __restrict__ starts,
                                                    const int2* __restrict__ arena,
                                                    const float* __restrict__ tmp,
                                                    float* __restrict__ out,
                                                    int N, int M) {
    int p = blockIdx.x * 8 + (threadIdx.x >> 5);
    if (p >= M) return;
    const int lane = threadIdx.x & 31;
    int c   = p / N;
    int row = p - c * N;
    int s = starts[p];
    int n = starts[p + 1] - s;
    const float* tc = tmp + c * D_C + lane;

    float acc = 0.f;
    int base = 0;
    for (; base + 16 <= n; base += 16) {
        int2 r[16];
        #pragma unroll
        for (int j = 0; j < 16; ++j) r[j] = arena[s + base + j];
        #pragma unroll
        for (int j = 0; j < 16; ++j)
            acc = fmaf(__int_as_float(r[j].y), tc[(size_t)(r[j].x & 0x1FFFF) * D_OUT], acc);
    }
    if (base + 8 <= n) {
        int2 r[8];
        #pragma unroll
        for (int j = 0; j < 8; ++j) r[j] = arena[s + base + j];
        #pragma unroll
        for (int j = 0; j < 8; ++j)
            acc = fmaf(__int_as_float(r[j].y), tc[(size_t)(r[j].x & 0x1FFFF) * D_OUT], acc);
        base += 8;
    }
    for (; base < n; ++base) {
        int2 rr = arena[s + base];
        acc = fmaf(__int_as_float(rr.y), tc[(size_t)(rr.x & 0x1FFFF) * D_OUT], acc);
    }
    out[(size_t)row * D_OUT + c * D_C + lane] = fmaxf(acc, 0.f);
}

// ---- fallback: atomic push + relu ----------------------------------------
__global__ __launch_bounds__(256) void scatter_kernel(const int* __restrict__ rows,
                                                      const int* __restrict__ cols,
                                                      const float* __restrict__ vals,
                                                      const float* __restrict__ tmp,
                                                      float* __restrict__ out,
                                                      long long totalEdges, int E) {
    long long gid = (long long)blockIdx.x * 8 + (threadIdx.x >> 5);
    if (gid >= totalEdges) return;
    const int lane = threadIdx.x & 31;
    const long long e1 = E, e2 = 2LL * E, e3 = 3LL * E;
    int c = (gid >= e3) ? 3 : (gid >= e2) ? 2 : (gid >= e1) ? 1 : 0;
    const float tv = tmp[(size_t)cols[gid] * D_OUT + c * D_C + lane];
    atomicAdd(&out[(size_t)rows[gid] * D_OUT + c * D_C + lane], tv * vals[gid]);
}

__global__ void relu_kernel(float* __restrict__ out, int n4) {
    int i = blockIdx.x * blockDim.x + threadIdx.x;
    if (i < n4) {
        float4 v = reinterpret_cast<float4*>(out)[i];
        v.x = fmaxf(v.x, 0.f); v.y = fmaxf(v.y, 0.f);
        v.z = fmaxf(v.z, 0.f); v.w = fmaxf(v.w, 0.f);
        reinterpret_cast<float4*>(out)[i] = v;
    }
}

extern "C" void kernel_launch(void* const* d_in, const int* in_sizes, int n_in,
                              void* d_out, int out_size, void* d_ws, size_t ws_size,
                              hipStream_t stream) {
    const float* x    = (const float*)d_in[0];
    const float* W    = (const float*)d_in[1];
    const int*   rows = (const int*)d_in[2];
    const int*   cols = (const int*)d_in[3];
    const float* vals = (const float*)d_in[4];
    float* out = (float*)d_out;

    const int N  = in_sizes[0] / D_IN;      // 100000
    const int CE = in_sizes[2];             // 6,400,000
    const int E  = CE / NUM_C;
    const int NB = (N + RB - 1) >> RB_LOG;  // 391
    const int MB = NUM_C * NB;              // 1564
    const int M  = NUM_C * N;               // 400,000

    // workspace layout
    size_t off = 0;
    float* tmp   = (float*)((char*)d_ws + off); off += (size_t)N * D_OUT * 4;
    int* bcnt    = (int*)((char*)d_ws + off);   off += (size_t)MB * 4;
    int* bstart  = (int*)((char*)d_ws + off);   off += (size_t)MB * 4;
    int* bhead   = (int*)((char*)d_ws + off);   off += (size_t)MB * 4;
    int* starts  = (int*)((char*)d_ws + off);   off += (size_t)(M + 1) * 4;
    off = (off + 15) & ~(size_t)15;
    int2* arena  = (int2*)((char*)d_ws + off);  off += (size_t)CE * 8;
    size_t off_a = off + (size_t)CE * 8;        // layout A: separate sorted arena
    int2* arena2 = (int2*)((char*)d_ws + off);
    const bool okB = (off   <= ws_size) && (MB <= MB_MAX);
    const bool okA = (off_a <= ws_size) && (MB <= MB_MAX);
    if (okA) arena2 = (int2*)((char*)d_ws + off);   // arena2 after arena
    int2* sorted = okA ? arena2 : arena;

    const int gemmBlocks = (N + 63) / 64;
    gemm_kernel<<<gemmBlocks, 256, 0, stream>>>(x, W, tmp, N);

    if (okB) {
        hipMemsetAsync(bcnt, 0, (size_t)MB * 4, stream);
        const int histBlocks = (CE + 16383) / 16384;
        bucket_hist_kernel<<<histBlocks, 256, 0, stream>>>(rows, bcnt, CE, E, NB, MB);
        bucket_scan_kernel<<<1, 1024, 0, stream>>>(bcnt, bstart, bhead, starts, MB, M);
        const int partBlocks = (CE + 4095) / 4096;
        partition_kernel<<<partBlocks, 256, 0, stream>>>(rows, cols, vals, bhead, arena, CE, E, NB, MB);
        rowsort_kernel<<<MB, 256, 0, stream>>>(bstart, bcnt, arena, sorted, starts, N, NB);
        const int pullBlocks = (M + 7) / 8;
        pull2_kernel<<<pullBlocks, 256, 0, stream>>>(starts, sorted, tmp, out, N, M);
    } else {
        hipMemsetAsync(d_out, 0, (size_t)out_size * sizeof(float), stream);
        const int scatterBlocks = (CE + 7) / 8;
        scatter_kernel<<<scatterBlocks, 256, 0, stream>>>(rows, cols, vals, tmp, out, (long long)CE, E);
        const int n4 = out_size / 4;
        relu_kernel<<<(n4 + 255) / 256, 256, 0, stream>>>(out, n4);
    }
}

// Round 5
// 406.223 us; speedup vs baseline: 3.5372x; 1.1581x over previous
//
#include <hip/hip_runtime.h>
#include <hip/hip_bf16.h>
#include <hip/hip_fp16.h>

// Problem constants: N=100000, D_IN=256, C=4, D_C=32, E=1.6e6
#define D_IN 256
#define D_OUT 128   // C * D_C
#define D_C 32
#define NUM_C 4
#define RB_LOG 8
#define RB 256          // rows per bucket
#define MB_MAX 1600     // LDS bucket-array capacity
#define STASH 20        // rowsort per-thread record stash (20*256 = 5120 >= bucket max)

// ---- GEMM: tmp[N][128] = x[N][256] @ W[256][128], fp16 output ------------
__global__ __launch_bounds__(256) void gemm_kernel(const float* __restrict__ x,
                                                   const float* __restrict__ W,
                                                   __half* __restrict__ tmp,
                                                   int Nrows) {
    __shared__ float xs[64][68];
    __shared__ float ws[32][128];
    const int t    = threadIdx.x;
    const int brow = blockIdx.x * 64;
    const int lane = t & 31;
    const int rg   = t >> 5;
    const int row0 = rg * 8;
    const int col0 = lane * 4;

    float acc[8][4] = {};

    for (int k0 = 0; k0 < D_IN; k0 += 32) {
        #pragma unroll
        for (int s = 0; s < 2; ++s) {
            int i = t + 256 * s;
            int r = i >> 3, kq = i & 7;
            float4 v = make_float4(0.f, 0.f, 0.f, 0.f);
            if (brow + r < Nrows)
                v = *reinterpret_cast<const float4*>(&x[(size_t)(brow + r) * D_IN + k0 + kq * 4]);
            *reinterpret_cast<float4*>(&xs[r][kq * 4]) = v;
        }
        const float4* wg  = reinterpret_cast<const float4*>(W + (size_t)k0 * D_OUT);
        float4*       ws4 = reinterpret_cast<float4*>(&ws[0][0]);
        #pragma unroll
        for (int s = 0; s < 4; ++s) ws4[t + 256 * s] = wg[t + 256 * s];
        __syncthreads();

        #pragma unroll
        for (int kk = 0; kk < 32; kk += 4) {
            float4 xv[8];
            #pragma unroll
            for (int r = 0; r < 8; ++r)
                xv[r] = *reinterpret_cast<const float4*>(&xs[row0 + r][kk]);
            #pragma unroll
            for (int q = 0; q < 4; ++q) {
                float4 wv = *reinterpret_cast<const float4*>(&ws[kk + q][col0]);
                #pragma unroll
                for (int r = 0; r < 8; ++r) {
                    float xsc = reinterpret_cast<const float*>(&xv[r])[q];
                    acc[r][0] = fmaf(xsc, wv.x, acc[r][0]);
                    acc[r][1] = fmaf(xsc, wv.y, acc[r][1]);
                    acc[r][2] = fmaf(xsc, wv.z, acc[r][2]);
                    acc[r][3] = fmaf(xsc, wv.w, acc[r][3]);
                }
            }
        }
        __syncthreads();
    }

    #pragma unroll
    for (int r = 0; r < 8; ++r) {
        int row = brow + row0 + r;
        if (row < Nrows) {
            __half2 h01 = __floats2half2_rn(acc[r][0], acc[r][1]);
            __half2 h23 = __floats2half2_rn(acc[r][2], acc[r][3]);
            uint2 pk;
            pk.x = *reinterpret_cast<unsigned int*>(&h01);
            pk.y = *reinterpret_cast<unsigned int*>(&h23);
            *reinterpret_cast<uint2*>(&tmp[(size_t)row * D_OUT + col0]) = pk;
        }
    }
}

// ---- bucket histogram (LDS-aggregated, int4 loads) -----------------------
__global__ __launch_bounds__(256) void bucket_hist_kernel(const int* __restrict__ rows,
                                                          int* __restrict__ bcnt,
                                                          int CE, int E, int NB, int MB) {
    __shared__ int h[MB_MAX];
    for (int i = threadIdx.x; i < MB; i += 256) h[i] = 0;
    __syncthreads();
    const int CE4 = CE >> 2;
    const int4* rows4 = reinterpret_cast<const int4*>(rows);
    int base4 = blockIdx.x * 4096;
    #pragma unroll 4
    for (int i = 0; i < 16; ++i) {
        int i4 = base4 + threadIdx.x + i * 256;
        if (i4 < CE4) {
            int e0 = i4 << 2;
            int c = (e0 >= 3 * E) ? 3 : (e0 >= 2 * E) ? 2 : (e0 >= E) ? 1 : 0;
            int4 rv = rows4[i4];
            atomicAdd(&h[c * NB + (rv.x >> RB_LOG)], 1);
            atomicAdd(&h[c * NB + (rv.y >> RB_LOG)], 1);
            atomicAdd(&h[c * NB + (rv.z >> RB_LOG)], 1);
            atomicAdd(&h[c * NB + (rv.w >> RB_LOG)], 1);
        }
    }
    // scalar tail (CE % 4)
    if (blockIdx.x == 0 && threadIdx.x < (CE & 3)) {
        int e = (CE4 << 2) + threadIdx.x;
        int c = (e >= 3 * E) ? 3 : (e >= 2 * E) ? 2 : (e >= E) ? 1 : 0;
        atomicAdd(&h[c * NB + (rows[e] >> RB_LOG)], 1);
    }
    __syncthreads();
    for (int i = threadIdx.x; i < MB; i += 256)
        if (h[i]) atomicAdd(&bcnt[i], h[i]);
}

// ---- scan bucket counts; also writes the starts[] sentinel ---------------
__global__ __launch_bounds__(1024) void bucket_scan_kernel(const int* __restrict__ bcnt,
                                                           int* __restrict__ bstart,
                                                           int* __restrict__ bhead,
                                                           int* __restrict__ starts,
                                                           int MB, int M) {
    __shared__ int sd[1024];
    int t = threadIdx.x;
    int i0 = 2 * t, i1 = 2 * t + 1;
    int v0 = (i0 < MB) ? bcnt[i0] : 0;
    int v1 = (i1 < MB) ? bcnt[i1] : 0;
    int ps = v0 + v1;
    sd[t] = ps; __syncthreads();
    for (int off = 1; off < 1024; off <<= 1) {
        int add = (t >= off) ? sd[t - off] : 0;
        __syncthreads();
        sd[t] += add;
        __syncthreads();
    }
    int excl = sd[t] - ps;
    if (i0 < MB) { bstart[i0] = excl;      bhead[i0] = excl; }
    if (i1 < MB) { bstart[i1] = excl + v0; bhead[i1] = excl + v0; }
    if (t == 1023) starts[M] = sd[1023];   // sentinel = total edge count
}

// ---- partition: 8192 edges/block into bucket-contiguous arena ------------
// packed: b[0:11) | rank[11:24) | rowlocal[24:32);  b==2047 marks invalid
// arena record: x = col | (rowlocal<<17), y = val bits
__global__ __launch_bounds__(256) void partition_kernel(const int* __restrict__ rows,
                                                        const int* __restrict__ cols,
                                                        const float* __restrict__ vals,
                                                        int* __restrict__ bhead,
                                                        int2* __restrict__ arena,
                                                        int CE, int E, int NB, int MB) {
    __shared__ int lcnt[MB_MAX];
    __shared__ int lbase[MB_MAX];
    for (int i = threadIdx.x; i < MB; i += 256) lcnt[i] = 0;
    __syncthreads();
    int base = blockIdx.x * 8192;
    unsigned packed[32];
    #pragma unroll
    for (int i = 0; i < 32; ++i) {
        int e = base + threadIdx.x + i * 256;
        unsigned pk = 2047u;
        if (e < CE) {
            int c = (e >= 3 * E) ? 3 : (e >= 2 * E) ? 2 : (e >= E) ? 1 : 0;
            int r = rows[e];
            int b = c * NB + (r >> RB_LOG);
            int rank = atomicAdd(&lcnt[b], 1);
            pk = (unsigned)b | ((unsigned)rank << 11) | ((unsigned)(r & (RB - 1)) << 24);
        }
        packed[i] = pk;
    }
    __syncthreads();
    for (int b = threadIdx.x; b < MB; b += 256) {
        int n = lcnt[b];
        lbase[b] = n ? atomicAdd(&bhead[b], n) : 0;
    }
    __syncthreads();
    #pragma unroll
    for (int i = 0; i < 32; ++i) {
        unsigned pk = packed[i];
        int b = pk & 2047u;
        if (b != 2047) {
            int e    = base + threadIdx.x + i * 256;
            int rank = (pk >> 11) & 8191u;
            int rl   = pk >> 24;
            arena[lbase[b] + rank] = make_int2(cols[e] | (rl << 17), __float_as_int(vals[e]));
        }
    }
}

// ---- in-bucket counting sort by rowlocal; emits per-row starts -----------
__global__ __launch_bounds__(256) void rowsort_kernel(const int* __restrict__ bstart,
                                                      const int* __restrict__ bcnt,
                                                      const int2* __restrict__ src,
                                                      int2* __restrict__ dst,
                                                      int* __restrict__ starts,
                                                      int N, int NB) {
    __shared__ int lcnt[RB];
    __shared__ int sd[RB];
    int b = blockIdx.x;
    int c = b / NB, rb = b - c * NB;
    int t = threadIdx.x;
    int s = bstart[b], n = bcnt[b];

    int2 recs[STASH];
    #pragma unroll
    for (int k = 0; k < STASH; ++k) {
        int i = t + k * 256;
        if (i < n) recs[k] = src[s + i];
    }
    lcnt[t] = 0;
    __syncthreads();
    #pragma unroll
    for (int k = 0; k < STASH; ++k) {
        int i = t + k * 256;
        if (i < n) atomicAdd(&lcnt[(recs[k].x >> 17) & 255], 1);
    }
    for (int i = t + STASH * 256; i < n; i += 256)
        atomicAdd(&lcnt[(src[s + i].x >> 17) & 255], 1);
    __syncthreads();
    int v = lcnt[t];
    sd[t] = v; __syncthreads();
    for (int off = 1; off < 256; off <<= 1) {
        int add = (t >= off) ? sd[t - off] : 0;
        __syncthreads();
        sd[t] += add;
        __syncthreads();
    }
    int excl = sd[t] - v;
    int grow = (rb << RB_LOG) + t;
    if (grow < N) starts[c * N + grow] = s + excl;
    __syncthreads();
    lcnt[t] = excl;   // reuse as heads
    __syncthreads();
    #pragma unroll
    for (int k = 0; k < STASH; ++k) {
        int i = t + k * 256;
        if (i < n) {
            int rl  = (recs[k].x >> 17) & 255;
            int pos = atomicAdd(&lcnt[rl], 1);
            dst[s + pos] = recs[k];
        }
    }
    for (int i = t + STASH * 256; i < n; i += 256) {
        int2 rec = src[s + i];
        int rl  = (rec.x >> 17) & 255;
        int pos = atomicAdd(&lcnt[rl], 1);
        dst[s + pos] = rec;
    }
}

// ---- pull: 16-lane group per (class,row); half2 gather; fused ReLU -------
__global__ __launch_bounds__(256) void pull2_kernel(const int* __restrict__ starts,
                                                    const int2* __restrict__ arena,
                                                    const __half2* __restrict__ tmp2,
                                                    float* __restrict__ out,
                                                    int N, int M) {
    int p = blockIdx.x * 16 + (threadIdx.x >> 4);
    if (p >= M) return;
    const int lf = threadIdx.x & 15;
    int c   = p / N;
    int row = p - c * N;
    int s = starts[p];
    int n = starts[p + 1] - s;
    const __half2* tc = tmp2 + c * 16 + lf;   // row stride 64 half2

    float2 acc = make_float2(0.f, 0.f);
    int base = 0;
    for (; base + 16 <= n; base += 16) {
        int2 r[16];
        #pragma unroll
        for (int j = 0; j < 16; ++j) r[j] = arena[s + base + j];
        #pragma unroll
        for (int j = 0; j < 16; ++j) {
            float  v  = __int_as_float(r[j].y);
            float2 tv = __half22float2(tc[(size_t)(r[j].x & 0x1FFFF) * 64]);
            acc.x = fmaf(v, tv.x, acc.x);
            acc.y = fmaf(v, tv.y, acc.y);
        }
    }
    if (base + 8 <= n) {
        int2 r[8];
        #pragma unroll
        for (int j = 0; j < 8; ++j) r[j] = arena[s + base + j];
        #pragma unroll
        for (int j = 0; j < 8; ++j) {
            float  v  = __int_as_float(r[j].y);
            float2 tv = __half22float2(tc[(size_t)(r[j].x & 0x1FFFF) * 64]);
            acc.x = fmaf(v, tv.x, acc.x);
            acc.y = fmaf(v, tv.y, acc.y);
        }
        base += 8;
    }
    for (; base < n; ++base) {
        int2 rr = arena[s + base];
        float  v  = __int_as_float(rr.y);
        float2 tv = __half22float2(tc[(size_t)(rr.x & 0x1FFFF) * 64]);
        acc.x = fmaf(v, tv.x, acc.x);
        acc.y = fmaf(v, tv.y, acc.y);
    }
    *reinterpret_cast<float2*>(&out[(size_t)row * D_OUT + c * D_C + 2 * lf]) =
        make_float2(fmaxf(acc.x, 0.f), fmaxf(acc.y, 0.f));
}

// ---- fallback: atomic push + relu ----------------------------------------
__global__ __launch_bounds__(256) void scatter_kernel(const int* __restrict__ rows,
                                                      const int* __restrict__ cols,
                                                      const float* __restrict__ vals,
                                                      const __half* __restrict__ tmp,
                                                      float* __restrict__ out,
                                                      long long totalEdges, int E) {
    long long gid = (long long)blockIdx.x * 8 + (threadIdx.x >> 5);
    if (gid >= totalEdges) return;
    const int lane = threadIdx.x & 31;
    const long long e1 = E, e2 = 2LL * E, e3 = 3LL * E;
    int c = (gid >= e3) ? 3 : (gid >= e2) ? 2 : (gid >= e1) ? 1 : 0;
    const float tv = __half2float(tmp[(size_t)cols[gid] * D_OUT + c * D_C + lane]);
    atomicAdd(&out[(size_t)rows[gid] * D_OUT + c * D_C + lane], tv * vals[gid]);
}

__global__ void relu_kernel(float* __restrict__ out, int n4) {
    int i = blockIdx.x * blockDim.x + threadIdx.x;
    if (i < n4) {
        float4 v = reinterpret_cast<float4*>(out)[i];
        v.x = fmaxf(v.x, 0.f); v.y = fmaxf(v.y, 0.f);
        v.z = fmaxf(v.z, 0.f); v.w = fmaxf(v.w, 0.f);
        reinterpret_cast<float4*>(out)[i] = v;
    }
}

extern "C" void kernel_launch(void* const* d_in, const int* in_sizes, int n_in,
                              void* d_out, int out_size, void* d_ws, size_t ws_size,
                              hipStream_t stream) {
    const float* x    = (const float*)d_in[0];
    const float* W    = (const float*)d_in[1];
    const int*   rows = (const int*)d_in[2];
    const int*   cols = (const int*)d_in[3];
    const float* vals = (const float*)d_in[4];
    float* out = (float*)d_out;

    const int N  = in_sizes[0] / D_IN;      // 100000
    const int CE = in_sizes[2];             // 6,400,000
    const int E  = CE / NUM_C;
    const int NB = (N + RB - 1) >> RB_LOG;  // 391
    const int MB = NUM_C * NB;              // 1564
    const int M  = NUM_C * N;               // 400,000

    // workspace layout
    size_t off = 0;
    __half* tmp  = (__half*)((char*)d_ws + off); off += (size_t)N * D_OUT * 2;
    off = (off + 15) & ~(size_t)15;
    int* bcnt    = (int*)((char*)d_ws + off);   off += (size_t)MB * 4;
    int* bstart  = (int*)((char*)d_ws + off);   off += (size_t)MB * 4;
    int* bhead   = (int*)((char*)d_ws + off);   off += (size_t)MB * 4;
    int* starts  = (int*)((char*)d_ws + off);   off += (size_t)(M + 1) * 4;
    off = (off + 15) & ~(size_t)15;
    int2* arena  = (int2*)((char*)d_ws + off);  off += (size_t)CE * 8;
    int2* arena2 = (int2*)((char*)d_ws + off);
    size_t off_a = off + (size_t)CE * 8;
    const bool okB = (off   <= ws_size) && (MB <= MB_MAX);
    const bool okA = (off_a <= ws_size) && (MB <= MB_MAX);
    int2* sorted = okA ? arena2 : arena;

    const int gemmBlocks = (N + 63) / 64;
    gemm_kernel<<<gemmBlocks, 256, 0, stream>>>(x, W, tmp, N);

    if (okB) {
        hipMemsetAsync(bcnt, 0, (size_t)MB * 4, stream);
        const int histBlocks = ((CE >> 2) + 4095) / 4096;
        bucket_hist_kernel<<<histBlocks, 256, 0, stream>>>(rows, bcnt, CE, E, NB, MB);
        bucket_scan_kernel<<<1, 1024, 0, stream>>>(bcnt, bstart, bhead, starts, MB, M);
        const int partBlocks = (CE + 8191) / 8192;
        partition_kernel<<<partBlocks, 256, 0, stream>>>(rows, cols, vals, bhead, arena, CE, E, NB, MB);
        rowsort_kernel<<<MB, 256, 0, stream>>>(bstart, bcnt, arena, sorted, starts, N, NB);
        const int pullBlocks = (M + 15) / 16;
        pull2_kernel<<<pullBlocks, 256, 0, stream>>>(starts, sorted,
                                                     reinterpret_cast<const __half2*>(tmp), out, N, M);
    } else {
        hipMemsetAsync(d_out, 0, (size_t)out_size * sizeof(float), stream);
        const int scatterBlocks = (CE + 7) / 8;
        scatter_kernel<<<scatterBlocks, 256, 0, stream>>>(rows, cols, vals, tmp, out, (long long)CE, E);
        const int n4 = out_size / 4;
        relu_kernel<<<(n4 + 255) / 256, 256, 0, stream>>>(out, n4);
    }
}

// Round 6
// 392.611 us; speedup vs baseline: 3.6598x; 1.0347x over previous
//
#include <hip/hip_runtime.h>
#include <hip/hip_bf16.h>
#include <hip/hip_fp16.h>

// Problem constants: N=100000, D_IN=256, C=4, D_C=32, E=1.6e6
#define D_IN 256
#define D_OUT 128   // C * D_C
#define D_C 32
#define NUM_C 4
#define RB_LOG 8
#define RB 256          // rows per bucket
#define MB_MAX 1600     // LDS bucket-array capacity
#define STASH 20        // rowsort per-thread record stash (20*256 = 5120 >= bucket max)

// ---- GEMM: tmp[N][128] = x[N][256] @ W[256][128], fp16 output ------------
__global__ __launch_bounds__(256) void gemm_kernel(const float* __restrict__ x,
                                                   const float* __restrict__ W,
                                                   __half* __restrict__ tmp,
                                                   int Nrows) {
    __shared__ float xs[64][68];
    __shared__ float ws[32][128];
    const int t    = threadIdx.x;
    const int brow = blockIdx.x * 64;
    const int lane = t & 31;
    const int rg   = t >> 5;
    const int row0 = rg * 8;
    const int col0 = lane * 4;

    float acc[8][4] = {};

    for (int k0 = 0; k0 < D_IN; k0 += 32) {
        #pragma unroll
        for (int s = 0; s < 2; ++s) {
            int i = t + 256 * s;
            int r = i >> 3, kq = i & 7;
            float4 v = make_float4(0.f, 0.f, 0.f, 0.f);
            if (brow + r < Nrows)
                v = *reinterpret_cast<const float4*>(&x[(size_t)(brow + r) * D_IN + k0 + kq * 4]);
            *reinterpret_cast<float4*>(&xs[r][kq * 4]) = v;
        }
        const float4* wg  = reinterpret_cast<const float4*>(W + (size_t)k0 * D_OUT);
        float4*       ws4 = reinterpret_cast<float4*>(&ws[0][0]);
        #pragma unroll
        for (int s = 0; s < 4; ++s) ws4[t + 256 * s] = wg[t + 256 * s];
        __syncthreads();

        #pragma unroll
        for (int kk = 0; kk < 32; kk += 4) {
            float4 xv[8];
            #pragma unroll
            for (int r = 0; r < 8; ++r)
                xv[r] = *reinterpret_cast<const float4*>(&xs[row0 + r][kk]);
            #pragma unroll
            for (int q = 0; q < 4; ++q) {
                float4 wv = *reinterpret_cast<const float4*>(&ws[kk + q][col0]);
                #pragma unroll
                for (int r = 0; r < 8; ++r) {
                    float xsc = reinterpret_cast<const float*>(&xv[r])[q];
                    acc[r][0] = fmaf(xsc, wv.x, acc[r][0]);
                    acc[r][1] = fmaf(xsc, wv.y, acc[r][1]);
                    acc[r][2] = fmaf(xsc, wv.z, acc[r][2]);
                    acc[r][3] = fmaf(xsc, wv.w, acc[r][3]);
                }
            }
        }
        __syncthreads();
    }

    #pragma unroll
    for (int r = 0; r < 8; ++r) {
        int row = brow + row0 + r;
        if (row < Nrows) {
            __half2 h01 = __floats2half2_rn(acc[r][0], acc[r][1]);
            __half2 h23 = __floats2half2_rn(acc[r][2], acc[r][3]);
            uint2 pk;
            pk.x = *reinterpret_cast<unsigned int*>(&h01);
            pk.y = *reinterpret_cast<unsigned int*>(&h23);
            *reinterpret_cast<uint2*>(&tmp[(size_t)row * D_OUT + col0]) = pk;
        }
    }
}

// ---- bucket histogram (LDS-aggregated, int4 loads) -----------------------
__global__ __launch_bounds__(256) void bucket_hist_kernel(const int* __restrict__ rows,
                                                          int* __restrict__ bcnt,
                                                          int CE, int E, int NB, int MB) {
    __shared__ int h[MB_MAX];
    for (int i = threadIdx.x; i < MB; i += 256) h[i] = 0;
    __syncthreads();
    const int CE4 = CE >> 2;
    const int4* rows4 = reinterpret_cast<const int4*>(rows);
    int base4 = blockIdx.x * 4096;
    #pragma unroll 4
    for (int i = 0; i < 16; ++i) {
        int i4 = base4 + threadIdx.x + i * 256;
        if (i4 < CE4) {
            int e0 = i4 << 2;
            int c = (e0 >= 3 * E) ? 3 : (e0 >= 2 * E) ? 2 : (e0 >= E) ? 1 : 0;
            int4 rv = rows4[i4];
            atomicAdd(&h[c * NB + (rv.x >> RB_LOG)], 1);
            atomicAdd(&h[c * NB + (rv.y >> RB_LOG)], 1);
            atomicAdd(&h[c * NB + (rv.z >> RB_LOG)], 1);
            atomicAdd(&h[c * NB + (rv.w >> RB_LOG)], 1);
        }
    }
    // scalar tail (CE % 4)
    if (blockIdx.x == 0 && threadIdx.x < (CE & 3)) {
        int e = (CE4 << 2) + threadIdx.x;
        int c = (e >= 3 * E) ? 3 : (e >= 2 * E) ? 2 : (e >= E) ? 1 : 0;
        atomicAdd(&h[c * NB + (rows[e] >> RB_LOG)], 1);
    }
    __syncthreads();
    for (int i = threadIdx.x; i < MB; i += 256)
        if (h[i]) atomicAdd(&bcnt[i], h[i]);
}

// ---- scan bucket counts; also writes the starts[] sentinel ---------------
__global__ __launch_bounds__(1024) void bucket_scan_kernel(const int* __restrict__ bcnt,
                                                           int* __restrict__ bstart,
                                                           int* __restrict__ bhead,
                                                           int* __restrict__ starts,
                                                           int MB, int M) {
    __shared__ int sd[1024];
    int t = threadIdx.x;
    int i0 = 2 * t, i1 = 2 * t + 1;
    int v0 = (i0 < MB) ? bcnt[i0] : 0;
    int v1 = (i1 < MB) ? bcnt[i1] : 0;
    int ps = v0 + v1;
    sd[t] = ps; __syncthreads();
    for (int off = 1; off < 1024; off <<= 1) {
        int add = (t >= off) ? sd[t - off] : 0;
        __syncthreads();
        sd[t] += add;
        __syncthreads();
    }
    int excl = sd[t] - ps;
    if (i0 < MB) { bstart[i0] = excl;      bhead[i0] = excl; }
    if (i1 < MB) { bstart[i1] = excl + v0; bhead[i1] = excl + v0; }
    if (t == 1023) starts[M] = sd[1023];   // sentinel = total edge count
}

// ---- partition: 8192 edges/block, 512 threads, 16 edges/thread -----------
// packed: b[0:11) | rank[11:24) | rowlocal[24:32);  b==2047 marks invalid
// arena record: x = col | (rowlocal<<17), y = val bits
__global__ __launch_bounds__(512) void partition_kernel(const int* __restrict__ rows,
                                                        const int* __restrict__ cols,
                                                        const float* __restrict__ vals,
                                                        int* __restrict__ bhead,
                                                        int2* __restrict__ arena,
                                                        int CE, int E, int NB, int MB) {
    __shared__ int lcnt[MB_MAX];
    __shared__ int lbase[MB_MAX];
    for (int i = threadIdx.x; i < MB; i += 512) lcnt[i] = 0;
    __syncthreads();
    int base = blockIdx.x * 8192;
    unsigned packed[16];
    #pragma unroll
    for (int i = 0; i < 16; ++i) {
        int e = base + threadIdx.x + i * 512;
        unsigned pk = 2047u;
        if (e < CE) {
            int c = (e >= 3 * E) ? 3 : (e >= 2 * E) ? 2 : (e >= E) ? 1 : 0;
            int r = rows[e];
            int b = c * NB + (r >> RB_LOG);
            int rank = atomicAdd(&lcnt[b], 1);
            pk = (unsigned)b | ((unsigned)rank << 11) | ((unsigned)(r & (RB - 1)) << 24);
        }
        packed[i] = pk;
    }
    __syncthreads();
    for (int b = threadIdx.x; b < MB; b += 512) {
        int n = lcnt[b];
        lbase[b] = n ? atomicAdd(&bhead[b], n) : 0;
    }
    __syncthreads();
    #pragma unroll
    for (int i = 0; i < 16; ++i) {
        unsigned pk = packed[i];
        int b = pk & 2047u;
        if (b != 2047) {
            int e    = base + threadIdx.x + i * 512;
            int rank = (pk >> 11) & 8191u;
            int rl   = pk >> 24;
            arena[lbase[b] + rank] = make_int2(cols[e] | (rl << 17), __float_as_int(vals[e]));
        }
    }
}

// ---- in-bucket counting sort by rowlocal; emits per-row starts -----------
__global__ __launch_bounds__(256) void rowsort_kernel(const int* __restrict__ bstart,
                                                      const int* __restrict__ bcnt,
                                                      const int2* __restrict__ src,
                                                      int2* __restrict__ dst,
                                                      int* __restrict__ starts,
                                                      int N, int NB) {
    __shared__ int lcnt[RB];
    __shared__ int sd[RB];
    int b = blockIdx.x;
    int c = b / NB, rb = b - c * NB;
    int t = threadIdx.x;
    int s = bstart[b], n = bcnt[b];

    int2 recs[STASH];
    #pragma unroll
    for (int k = 0; k < STASH; ++k) {
        int i = t + k * 256;
        if (i < n) recs[k] = src[s + i];
    }
    lcnt[t] = 0;
    __syncthreads();
    #pragma unroll
    for (int k = 0; k < STASH; ++k) {
        int i = t + k * 256;
        if (i < n) atomicAdd(&lcnt[(recs[k].x >> 17) & 255], 1);
    }
    for (int i = t + STASH * 256; i < n; i += 256)
        atomicAdd(&lcnt[(src[s + i].x >> 17) & 255], 1);
    __syncthreads();
    int v = lcnt[t];
    sd[t] = v; __syncthreads();
    for (int off = 1; off < 256; off <<= 1) {
        int add = (t >= off) ? sd[t - off] : 0;
        __syncthreads();
        sd[t] += add;
        __syncthreads();
    }
    int excl = sd[t] - v;
    int grow = (rb << RB_LOG) + t;
    if (grow < N) starts[c * N + grow] = s + excl;
    __syncthreads();
    lcnt[t] = excl;   // reuse as heads
    __syncthreads();
    #pragma unroll
    for (int k = 0; k < STASH; ++k) {
        int i = t + k * 256;
        if (i < n) {
            int rl  = (recs[k].x >> 17) & 255;
            int pos = atomicAdd(&lcnt[rl], 1);
            dst[s + pos] = recs[k];
        }
    }
    for (int i = t + STASH * 256; i < n; i += 256) {
        int2 rec = src[s + i];
        int rl  = (rec.x >> 17) & 255;
        int pos = atomicAdd(&lcnt[rl], 1);
        dst[s + pos] = rec;
    }
}

// ---- pull: 16-lane group per (class,row); half2 gather; fused ReLU -------
__global__ __launch_bounds__(256) void pull2_kernel(const int* __restrict__ starts,
                                                    const int2* __restrict__ arena,
                                                    const __half2* __restrict__ tmp2,
                                                    float* __restrict__ out,
                                                    int N, int M) {
    int p = blockIdx.x * 16 + (threadIdx.x >> 4);
    if (p >= M) return;
    const int lf = threadIdx.x & 15;
    int c   = p / N;
    int row = p - c * N;
    int s = starts[p];
    int n = starts[p + 1] - s;
    const __half2* tc = tmp2 + c * 16 + lf;   // row stride 64 half2

    float2 acc = make_float2(0.f, 0.f);
    int base = 0;
    for (; base + 16 <= n; base += 16) {
        int2 r[16];
        #pragma unroll
        for (int j = 0; j < 16; ++j) r[j] = arena[s + base + j];
        #pragma unroll
        for (int j = 0; j < 16; ++j) {
            float  v  = __int_as_float(r[j].y);
            float2 tv = __half22float2(tc[(size_t)(r[j].x & 0x1FFFF) * 64]);
            acc.x = fmaf(v, tv.x, acc.x);
            acc.y = fmaf(v, tv.y, acc.y);
        }
    }
    if (base + 8 <= n) {
        int2 r[8];
        #pragma unroll
        for (int j = 0; j < 8; ++j) r[j] = arena[s + base + j];
        #pragma unroll
        for (int j = 0; j < 8; ++j) {
            float  v  = __int_as_float(r[j].y);
            float2 tv = __half22float2(tc[(size_t)(r[j].x & 0x1FFFF) * 64]);
            acc.x = fmaf(v, tv.x, acc.x);
            acc.y = fmaf(v, tv.y, acc.y);
        }
        base += 8;
    }
    for (; base < n; ++base) {
        int2 rr = arena[s + base];
        float  v  = __int_as_float(rr.y);
        float2 tv = __half22float2(tc[(size_t)(rr.x & 0x1FFFF) * 64]);
        acc.x = fmaf(v, tv.x, acc.x);
        acc.y = fmaf(v, tv.y, acc.y);
    }
    *reinterpret_cast<float2*>(&out[(size_t)row * D_OUT + c * D_C + 2 * lf]) =
        make_float2(fmaxf(acc.x, 0.f), fmaxf(acc.y, 0.f));
}

// ---- fallback: atomic push + relu ----------------------------------------
__global__ __launch_bounds__(256) void scatter_kernel(const int* __restrict__ rows,
                                                      const int* __restrict__ cols,
                                                      const float* __restrict__ vals,
                                                      const __half* __restrict__ tmp,
                                                      float* __restrict__ out,
                                                      long long totalEdges, int E) {
    long long gid = (long long)blockIdx.x * 8 + (threadIdx.x >> 5);
    if (gid >= totalEdges) return;
    const int lane = threadIdx.x & 31;
    const long long e1 = E, e2 = 2LL * E, e3 = 3LL * E;
    int c = (gid >= e3) ? 3 : (gid >= e2) ? 2 : (gid >= e1) ? 1 : 0;
    const float tv = __half2float(tmp[(size_t)cols[gid] * D_OUT + c * D_C + lane]);
    atomicAdd(&out[(size_t)rows[gid] * D_OUT + c * D_C + lane], tv * vals[gid]);
}

__global__ void relu_kernel(float* __restrict__ out, int n4) {
    int i = blockIdx.x * blockDim.x + threadIdx.x;
    if (i < n4) {
        float4 v = reinterpret_cast<float4*>(out)[i];
        v.x = fmaxf(v.x, 0.f); v.y = fmaxf(v.y, 0.f);
        v.z = fmaxf(v.z, 0.f); v.w = fmaxf(v.w, 0.f);
        reinterpret_cast<float4*>(out)[i] = v;
    }
}

extern "C" void kernel_launch(void* const* d_in, const int* in_sizes, int n_in,
                              void* d_out, int out_size, void* d_ws, size_t ws_size,
                              hipStream_t stream) {
    const float* x    = (const float*)d_in[0];
    const float* W    = (const float*)d_in[1];
    const int*   rows = (const int*)d_in[2];
    const int*   cols = (const int*)d_in[3];
    const float* vals = (const float*)d_in[4];
    float* out = (float*)d_out;

    const int N  = in_sizes[0] / D_IN;      // 100000
    const int CE = in_sizes[2];             // 6,400,000
    const int E  = CE / NUM_C;
    const int NB = (N + RB - 1) >> RB_LOG;  // 391
    const int MB = NUM_C * NB;              // 1564
    const int M  = NUM_C * N;               // 400,000

    // workspace layout
    size_t off = 0;
    __half* tmp  = (__half*)((char*)d_ws + off); off += (size_t)N * D_OUT * 2;
    off = (off + 15) & ~(size_t)15;
    int* bcnt    = (int*)((char*)d_ws + off);   off += (size_t)MB * 4;
    int* bstart  = (int*)((char*)d_ws + off);   off += (size_t)MB * 4;
    int* bhead   = (int*)((char*)d_ws + off);   off += (size_t)MB * 4;
    int* starts  = (int*)((char*)d_ws + off);   off += (size_t)(M + 1) * 4;
    off = (off + 15) & ~(size_t)15;
    int2* arena  = (int2*)((char*)d_ws + off);  off += (size_t)CE * 8;
    int2* arena2 = (int2*)((char*)d_ws + off);
    size_t off_a = off + (size_t)CE * 8;
    const bool okB = (off   <= ws_size) && (MB <= MB_MAX);
    const bool okA = (off_a <= ws_size) && (MB <= MB_MAX);
    int2* sorted = okA ? arena2 : arena;

    const int gemmBlocks = (N + 63) / 64;
    gemm_kernel<<<gemmBlocks, 256, 0, stream>>>(x, W, tmp, N);

    if (okB) {
        hipMemsetAsync(bcnt, 0, (size_t)MB * 4, stream);
        const int histBlocks = ((CE >> 2) + 4095) / 4096;
        bucket_hist_kernel<<<histBlocks, 256, 0, stream>>>(rows, bcnt, CE, E, NB, MB);
        bucket_scan_kernel<<<1, 1024, 0, stream>>>(bcnt, bstart, bhead, starts, MB, M);
        const int partBlocks = (CE + 8191) / 8192;
        partition_kernel<<<partBlocks, 512, 0, stream>>>(rows, cols, vals, bhead, arena, CE, E, NB, MB);
        rowsort_kernel<<<MB, 256, 0, stream>>>(bstart, bcnt, arena, sorted, starts, N, NB);
        const int pullBlocks = (M + 15) / 16;
        pull2_kernel<<<pullBlocks, 256, 0, stream>>>(starts, sorted,
                                                     reinterpret_cast<const __half2*>(tmp), out, N, M);
    } else {
        hipMemsetAsync(d_out, 0, (size_t)out_size * sizeof(float), stream);
        const int scatterBlocks = (CE + 7) / 8;
        scatter_kernel<<<scatterBlocks, 256, 0, stream>>>(rows, cols, vals, tmp, out, (long long)CE, E);
        const int n4 = out_size / 4;
        relu_kernel<<<(n4 + 255) / 256, 256, 0, stream>>>(out, n4);
    }
}

// Round 7
// 377.641 us; speedup vs baseline: 3.8049x; 1.0396x over previous
//
#include <hip/hip_runtime.h>
#include <hip/hip_bf16.h>
#include <hip/hip_fp16.h>

// Problem constants: N=100000, D_IN=256, C=4, D_C=32, E=1.6e6
#define D_IN 256
#define D_OUT 128   // C * D_C
#define D_C 32
#define NUM_C 4
#define RB_LOG 9
#define RB 512          // rows per bucket
#define MB_MAX 800      // bucket-array capacity (NUM_C * ceil(N/RB) = 784)
#define STASH 16        // rowsort per-thread record stash (16*512 = 8192 >= bucket max)

// ---- GEMM: tmp[N][128] = x[N][256] @ W[256][128], fp16 output ------------
__global__ __launch_bounds__(256) void gemm_kernel(const float* __restrict__ x,
                                                   const float* __restrict__ W,
                                                   __half* __restrict__ tmp,
                                                   int Nrows) {
    __shared__ float xs[64][68];
    __shared__ float ws[32][128];
    const int t    = threadIdx.x;
    const int brow = blockIdx.x * 64;
    const int lane = t & 31;
    const int rg   = t >> 5;
    const int row0 = rg * 8;
    const int col0 = lane * 4;

    float acc[8][4] = {};

    for (int k0 = 0; k0 < D_IN; k0 += 32) {
        #pragma unroll
        for (int s = 0; s < 2; ++s) {
            int i = t + 256 * s;
            int r = i >> 3, kq = i & 7;
            float4 v = make_float4(0.f, 0.f, 0.f, 0.f);
            if (brow + r < Nrows)
                v = *reinterpret_cast<const float4*>(&x[(size_t)(brow + r) * D_IN + k0 + kq * 4]);
            *reinterpret_cast<float4*>(&xs[r][kq * 4]) = v;
        }
        const float4* wg  = reinterpret_cast<const float4*>(W + (size_t)k0 * D_OUT);
        float4*       ws4 = reinterpret_cast<float4*>(&ws[0][0]);
        #pragma unroll
        for (int s = 0; s < 4; ++s) ws4[t + 256 * s] = wg[t + 256 * s];
        __syncthreads();

        #pragma unroll
        for (int kk = 0; kk < 32; kk += 4) {
            float4 xv[8];
            #pragma unroll
            for (int r = 0; r < 8; ++r)
                xv[r] = *reinterpret_cast<const float4*>(&xs[row0 + r][kk]);
            #pragma unroll
            for (int q = 0; q < 4; ++q) {
                float4 wv = *reinterpret_cast<const float4*>(&ws[kk + q][col0]);
                #pragma unroll
                for (int r = 0; r < 8; ++r) {
                    float xsc = reinterpret_cast<const float*>(&xv[r])[q];
                    acc[r][0] = fmaf(xsc, wv.x, acc[r][0]);
                    acc[r][1] = fmaf(xsc, wv.y, acc[r][1]);
                    acc[r][2] = fmaf(xsc, wv.z, acc[r][2]);
                    acc[r][3] = fmaf(xsc, wv.w, acc[r][3]);
                }
            }
        }
        __syncthreads();
    }

    #pragma unroll
    for (int r = 0; r < 8; ++r) {
        int row = brow + row0 + r;
        if (row < Nrows) {
            __half2 h01 = __floats2half2_rn(acc[r][0], acc[r][1]);
            __half2 h23 = __floats2half2_rn(acc[r][2], acc[r][3]);
            uint2 pk;
            pk.x = *reinterpret_cast<unsigned int*>(&h01);
            pk.y = *reinterpret_cast<unsigned int*>(&h23);
            *reinterpret_cast<uint2*>(&tmp[(size_t)row * D_OUT + col0]) = pk;
        }
    }
}

// ---- bucket histogram (LDS-aggregated, int4 loads) -----------------------
__global__ __launch_bounds__(256) void bucket_hist_kernel(const int* __restrict__ rows,
                                                          int* __restrict__ bcnt,
                                                          int CE, int E, int NB, int MB) {
    __shared__ int h[MB_MAX];
    for (int i = threadIdx.x; i < MB; i += 256) h[i] = 0;
    __syncthreads();
    const int CE4 = CE >> 2;
    const int4* rows4 = reinterpret_cast<const int4*>(rows);
    int base4 = blockIdx.x * 4096;
    #pragma unroll 4
    for (int i = 0; i < 16; ++i) {
        int i4 = base4 + threadIdx.x + i * 256;
        if (i4 < CE4) {
            int e0 = i4 << 2;
            int c = (e0 >= 3 * E) ? 3 : (e0 >= 2 * E) ? 2 : (e0 >= E) ? 1 : 0;
            int4 rv = rows4[i4];
            atomicAdd(&h[c * NB + (rv.x >> RB_LOG)], 1);
            atomicAdd(&h[c * NB + (rv.y >> RB_LOG)], 1);
            atomicAdd(&h[c * NB + (rv.z >> RB_LOG)], 1);
            atomicAdd(&h[c * NB + (rv.w >> RB_LOG)], 1);
        }
    }
    // scalar tail (CE % 4)
    if (blockIdx.x == 0 && threadIdx.x < (CE & 3)) {
        int e = (CE4 << 2) + threadIdx.x;
        int c = (e >= 3 * E) ? 3 : (e >= 2 * E) ? 2 : (e >= E) ? 1 : 0;
        atomicAdd(&h[c * NB + (rows[e] >> RB_LOG)], 1);
    }
    __syncthreads();
    for (int i = threadIdx.x; i < MB; i += 256)
        if (h[i]) atomicAdd(&bcnt[i], h[i]);
}

// ---- scan bucket counts; also writes the starts[] sentinel ---------------
__global__ __launch_bounds__(1024) void bucket_scan_kernel(const int* __restrict__ bcnt,
                                                           int* __restrict__ bstart,
                                                           int* __restrict__ bhead,
                                                           int* __restrict__ starts,
                                                           int MB, int M) {
    __shared__ int sd[1024];
    int t = threadIdx.x;
    int v = (t < MB) ? bcnt[t] : 0;
    sd[t] = v; __syncthreads();
    for (int off = 1; off < 1024; off <<= 1) {
        int add = (t >= off) ? sd[t - off] : 0;
        __syncthreads();
        sd[t] += add;
        __syncthreads();
    }
    int excl = sd[t] - v;
    if (t < MB) { bstart[t] = excl; bhead[t] = excl; }
    if (t == 1023) starts[M] = sd[1023];   // sentinel = total edge count
}

// ---- partition: 8192 edges/block, 512 threads, 16 edges/thread -----------
// packed: b[0:10) | rank[10:23) | rowlocal[23:32);  b==1023 marks invalid
// arena record: x = col | (rowlocal<<17), y = val bits
__global__ __launch_bounds__(512) void partition_kernel(const int* __restrict__ rows,
                                                        const int* __restrict__ cols,
                                                        const float* __restrict__ vals,
                                                        int* __restrict__ bhead,
                                                        int2* __restrict__ arena,
                                                        int CE, int E, int NB, int MB) {
    __shared__ int lcnt[MB_MAX];
    __shared__ int lbase[MB_MAX];
    for (int i = threadIdx.x; i < MB; i += 512) lcnt[i] = 0;
    __syncthreads();
    int base = blockIdx.x * 8192;
    unsigned packed[16];
    #pragma unroll
    for (int i = 0; i < 16; ++i) {
        int e = base + threadIdx.x + i * 512;
        unsigned pk = 1023u;
        if (e < CE) {
            int c = (e >= 3 * E) ? 3 : (e >= 2 * E) ? 2 : (e >= E) ? 1 : 0;
            int r = rows[e];
            int b = c * NB + (r >> RB_LOG);
            int rank = atomicAdd(&lcnt[b], 1);
            pk = (unsigned)b | ((unsigned)rank << 10) | ((unsigned)(r & (RB - 1)) << 23);
        }
        packed[i] = pk;
    }
    __syncthreads();
    for (int b = threadIdx.x; b < MB; b += 512) {
        int n = lcnt[b];
        lbase[b] = n ? atomicAdd(&bhead[b], n) : 0;
    }
    __syncthreads();
    #pragma unroll
    for (int i = 0; i < 16; ++i) {
        unsigned pk = packed[i];
        int b = pk & 1023u;
        if (b != 1023) {
            int e    = base + threadIdx.x + i * 512;
            int rank = (pk >> 10) & 8191u;
            int rl   = pk >> 23;
            arena[lbase[b] + rank] = make_int2(cols[e] | (rl << 17), __float_as_int(vals[e]));
        }
    }
}

// ---- in-bucket counting sort by rowlocal; emits per-row starts -----------
__global__ __launch_bounds__(512) void rowsort_kernel(const int* __restrict__ bstart,
                                                      const int* __restrict__ bcnt,
                                                      const int2* __restrict__ src,
                                                      int2* __restrict__ dst,
                                                      int* __restrict__ starts,
                                                      int N, int NB) {
    __shared__ int lcnt[RB];   // 512
    __shared__ int sd[RB];
    int b = blockIdx.x;
    int c = b / NB, rb = b - c * NB;
    int t = threadIdx.x;
    int s = bstart[b], n = bcnt[b];

    int2 recs[STASH];
    #pragma unroll
    for (int k = 0; k < STASH; ++k) {
        int i = t + k * 512;
        if (i < n) recs[k] = src[s + i];
    }
    lcnt[t] = 0;
    __syncthreads();
    #pragma unroll
    for (int k = 0; k < STASH; ++k) {
        int i = t + k * 512;
        if (i < n) atomicAdd(&lcnt[(recs[k].x >> 17) & (RB - 1)], 1);
    }
    for (int i = t + STASH * 512; i < n; i += 512)
        atomicAdd(&lcnt[(src[s + i].x >> 17) & (RB - 1)], 1);
    __syncthreads();
    int v = lcnt[t];
    sd[t] = v; __syncthreads();
    for (int off = 1; off < 512; off <<= 1) {
        int add = (t >= off) ? sd[t - off] : 0;
        __syncthreads();
        sd[t] += add;
        __syncthreads();
    }
    int excl = sd[t] - v;
    int grow = (rb << RB_LOG) + t;
    if (grow < N) starts[c * N + grow] = s + excl;
    __syncthreads();
    lcnt[t] = excl;   // reuse as heads
    __syncthreads();
    #pragma unroll
    for (int k = 0; k < STASH; ++k) {
        int i = t + k * 512;
        if (i < n) {
            int rl  = (recs[k].x >> 17) & (RB - 1);
            int pos = atomicAdd(&lcnt[rl], 1);
            dst[s + pos] = recs[k];
        }
    }
    // overflow placement (correct: dst is a separate buffer from src)
    for (int i = t + STASH * 512; i < n; i += 512) {
        int2 rec = src[s + i];
        int rl  = (rec.x >> 17) & (RB - 1);
        int pos = atomicAdd(&lcnt[rl], 1);
        dst[s + pos] = rec;
    }
}

// ---- pull: 16-lane group per (class,row); half2 gather; fused ReLU -------
__global__ __launch_bounds__(256) void pull2_kernel(const int* __restrict__ starts,
                                                    const int2* __restrict__ arena,
                                                    const __half2* __restrict__ tmp2,
                                                    float* __restrict__ out,
                                                    int N, int M) {
    int p = blockIdx.x * 16 + (threadIdx.x >> 4);
    if (p >= M) return;
    const int lf = threadIdx.x & 15;
    int c   = p / N;
    int row = p - c * N;
    int s = starts[p];
    int n = starts[p + 1] - s;
    const __half2* tc = tmp2 + c * 16 + lf;   // row stride 64 half2

    float2 acc = make_float2(0.f, 0.f);
    int base = 0;
    for (; base + 16 <= n; base += 16) {
        int2 r[16];
        #pragma unroll
        for (int j = 0; j < 16; ++j) r[j] = arena[s + base + j];
        #pragma unroll
        for (int j = 0; j < 16; ++j) {
            float  v  = __int_as_float(r[j].y);
            float2 tv = __half22float2(tc[(size_t)(r[j].x & 0x1FFFF) * 64]);
            acc.x = fmaf(v, tv.x, acc.x);
            acc.y = fmaf(v, tv.y, acc.y);
        }
    }
    if (base + 8 <= n) {
        int2 r[8];
        #pragma unroll
        for (int j = 0; j < 8; ++j) r[j] = arena[s + base + j];
        #pragma unroll
        for (int j = 0; j < 8; ++j) {
            float  v  = __int_as_float(r[j].y);
            float2 tv = __half22float2(tc[(size_t)(r[j].x & 0x1FFFF) * 64]);
            acc.x = fmaf(v, tv.x, acc.x);
            acc.y = fmaf(v, tv.y, acc.y);
        }
        base += 8;
    }
    for (; base < n; ++base) {
        int2 rr = arena[s + base];
        float  v  = __int_as_float(rr.y);
        float2 tv = __half22float2(tc[(size_t)(rr.x & 0x1FFFF) * 64]);
        acc.x = fmaf(v, tv.x, acc.x);
        acc.y = fmaf(v, tv.y, acc.y);
    }
    *reinterpret_cast<float2*>(&out[(size_t)row * D_OUT + c * D_C + 2 * lf]) =
        make_float2(fmaxf(acc.x, 0.f), fmaxf(acc.y, 0.f));
}

// ---- fallback: atomic push + relu ----------------------------------------
__global__ __launch_bounds__(256) void scatter_kernel(const int* __restrict__ rows,
                                                      const int* __restrict__ cols,
                                                      const float* __restrict__ vals,
                                                      const __half* __restrict__ tmp,
                                                      float* __restrict__ out,
                                                      long long totalEdges, int E) {
    long long gid = (long long)blockIdx.x * 8 + (threadIdx.x >> 5);
    if (gid >= totalEdges) return;
    const int lane = threadIdx.x & 31;
    const long long e1 = E, e2 = 2LL * E, e3 = 3LL * E;
    int c = (gid >= e3) ? 3 : (gid >= e2) ? 2 : (gid >= e1) ? 1 : 0;
    const float tv = __half2float(tmp[(size_t)cols[gid] * D_OUT + c * D_C + lane]);
    atomicAdd(&out[(size_t)rows[gid] * D_OUT + c * D_C + lane], tv * vals[gid]);
}

__global__ void relu_kernel(float* __restrict__ out, int n4) {
    int i = blockIdx.x * blockDim.x + threadIdx.x;
    if (i < n4) {
        float4 v = reinterpret_cast<float4*>(out)[i];
        v.x = fmaxf(v.x, 0.f); v.y = fmaxf(v.y, 0.f);
        v.z = fmaxf(v.z, 0.f); v.w = fmaxf(v.w, 0.f);
        reinterpret_cast<float4*>(out)[i] = v;
    }
}

extern "C" void kernel_launch(void* const* d_in, const int* in_sizes, int n_in,
                              void* d_out, int out_size, void* d_ws, size_t ws_size,
                              hipStream_t stream) {
    const float* x    = (const float*)d_in[0];
    const float* W    = (const float*)d_in[1];
    const int*   rows = (const int*)d_in[2];
    const int*   cols = (const int*)d_in[3];
    const float* vals = (const float*)d_in[4];
    float* out = (float*)d_out;

    const int N  = in_sizes[0] / D_IN;      // 100000
    const int CE = in_sizes[2];             // 6,400,000
    const int E  = CE / NUM_C;
    const int NB = (N + RB - 1) >> RB_LOG;  // 196
    const int MB = NUM_C * NB;              // 784
    const int M  = NUM_C * N;               // 400,000

    // workspace layout
    size_t off = 0;
    __half* tmp  = (__half*)((char*)d_ws + off); off += (size_t)N * D_OUT * 2;
    off = (off + 15) & ~(size_t)15;
    int* bcnt    = (int*)((char*)d_ws + off);   off += (size_t)MB * 4;
    int* bstart  = (int*)((char*)d_ws + off);   off += (size_t)MB * 4;
    int* bhead   = (int*)((char*)d_ws + off);   off += (size_t)MB * 4;
    int* starts  = (int*)((char*)d_ws + off);   off += (size_t)(M + 1) * 4;
    off = (off + 15) & ~(size_t)15;
    int2* arena  = (int2*)((char*)d_ws + off);  off += (size_t)CE * 8;
    int2* arena2 = (int2*)((char*)d_ws + off);
    size_t off_a = off + (size_t)CE * 8;
    const bool okB = (off   <= ws_size) && (MB <= MB_MAX) && (MB <= 1024);
    const bool okA = (off_a <= ws_size) && (MB <= MB_MAX) && (MB <= 1024);
    int2* sorted = okA ? arena2 : arena;

    const int gemmBlocks = (N + 63) / 64;
    gemm_kernel<<<gemmBlocks, 256, 0, stream>>>(x, W, tmp, N);

    if (okB) {
        hipMemsetAsync(bcnt, 0, (size_t)MB * 4, stream);
        const int histBlocks = ((CE >> 2) + 4095) / 4096;
        bucket_hist_kernel<<<histBlocks, 256, 0, stream>>>(rows, bcnt, CE, E, NB, MB);
        bucket_scan_kernel<<<1, 1024, 0, stream>>>(bcnt, bstart, bhead, starts, MB, M);
        const int partBlocks = (CE + 8191) / 8192;
        partition_kernel<<<partBlocks, 512, 0, stream>>>(rows, cols, vals, bhead, arena, CE, E, NB, MB);
        rowsort_kernel<<<MB, 512, 0, stream>>>(bstart, bcnt, arena, sorted, starts, N, NB);
        const int pullBlocks = (M + 15) / 16;
        pull2_kernel<<<pullBlocks, 256, 0, stream>>>(starts, sorted,
                                                     reinterpret_cast<const __half2*>(tmp), out, N, M);
    } else {
        hipMemsetAsync(d_out, 0, (size_t)out_size * sizeof(float), stream);
        const int scatterBlocks = (CE + 7) / 8;
        scatter_kernel<<<scatterBlocks, 256, 0, stream>>>(rows, cols, vals, tmp, out, (long long)CE, E);
        const int n4 = out_size / 4;
        relu_kernel<<<(n4 + 255) / 256, 256, 0, stream>>>(out, n4);
    }
}

// Round 8
// 357.040 us; speedup vs baseline: 4.0244x; 1.0577x over previous
//
#include <hip/hip_runtime.h>
#include <hip/hip_bf16.h>
#include <hip/hip_fp16.h>

// Problem constants: N=100000, D_IN=256, C=4, D_C=32, E=1.6e6
#define D_IN 256
#define D_OUT 128   // C * D_C
#define D_C 32
#define NUM_C 4
#define RB_LOG 10
#define RB 1024         // rows per bucket
#define MB_MAX 400      // bucket-array capacity (NUM_C * ceil(N/RB) = 392)
#define STASH 33        // rowsort stash: 33*512 = 16896 >= max bucket (~16.8k)

// ---- GEMM: tmp[c][N][32] (class-major fp16) = x @ W ----------------------
__global__ __launch_bounds__(256) void gemm_kernel(const float* __restrict__ x,
                                                   const float* __restrict__ W,
                                                   __half* __restrict__ tmp,
                                                   int Nrows) {
    __shared__ float xs[64][68];
    __shared__ float ws[32][128];
    const int t    = threadIdx.x;
    const int brow = blockIdx.x * 64;
    const int lane = t & 31;
    const int rg   = t >> 5;
    const int row0 = rg * 8;
    const int col0 = lane * 4;

    float acc[8][4] = {};

    for (int k0 = 0; k0 < D_IN; k0 += 32) {
        #pragma unroll
        for (int s = 0; s < 2; ++s) {
            int i = t + 256 * s;
            int r = i >> 3, kq = i & 7;
            float4 v = make_float4(0.f, 0.f, 0.f, 0.f);
            if (brow + r < Nrows)
                v = *reinterpret_cast<const float4*>(&x[(size_t)(brow + r) * D_IN + k0 + kq * 4]);
            *reinterpret_cast<float4*>(&xs[r][kq * 4]) = v;
        }
        const float4* wg  = reinterpret_cast<const float4*>(W + (size_t)k0 * D_OUT);
        float4*       ws4 = reinterpret_cast<float4*>(&ws[0][0]);
        #pragma unroll
        for (int s = 0; s < 4; ++s) ws4[t + 256 * s] = wg[t + 256 * s];
        __syncthreads();

        #pragma unroll
        for (int kk = 0; kk < 32; kk += 4) {
            float4 xv[8];
            #pragma unroll
            for (int r = 0; r < 8; ++r)
                xv[r] = *reinterpret_cast<const float4*>(&xs[row0 + r][kk]);
            #pragma unroll
            for (int q = 0; q < 4; ++q) {
                float4 wv = *reinterpret_cast<const float4*>(&ws[kk + q][col0]);
                #pragma unroll
                for (int r = 0; r < 8; ++r) {
                    float xsc = reinterpret_cast<const float*>(&xv[r])[q];
                    acc[r][0] = fmaf(xsc, wv.x, acc[r][0]);
                    acc[r][1] = fmaf(xsc, wv.y, acc[r][1]);
                    acc[r][2] = fmaf(xsc, wv.z, acc[r][2]);
                    acc[r][3] = fmaf(xsc, wv.w, acc[r][3]);
                }
            }
        }
        __syncthreads();
    }

    const int cls = lane >> 3;          // col0 / 32
    const int wc  = (lane & 7) * 4;     // col0 % 32
    #pragma unroll
    for (int r = 0; r < 8; ++r) {
        int row = brow + row0 + r;
        if (row < Nrows) {
            __half2 h01 = __floats2half2_rn(acc[r][0], acc[r][1]);
            __half2 h23 = __floats2half2_rn(acc[r][2], acc[r][3]);
            uint2 pk;
            pk.x = *reinterpret_cast<unsigned int*>(&h01);
            pk.y = *reinterpret_cast<unsigned int*>(&h23);
            *reinterpret_cast<uint2*>(&tmp[((size_t)cls * Nrows + row) * 32 + wc]) = pk;
        }
    }
}

// ---- bucket histogram (LDS-aggregated, int4 loads) -----------------------
__global__ __launch_bounds__(256) void bucket_hist_kernel(const int* __restrict__ rows,
                                                          int* __restrict__ bcnt,
                                                          int CE, int E, int NB, int MB) {
    __shared__ int h[MB_MAX];
    for (int i = threadIdx.x; i < MB; i += 256) h[i] = 0;
    __syncthreads();
    const int CE4 = CE >> 2;
    const int4* rows4 = reinterpret_cast<const int4*>(rows);
    int base4 = blockIdx.x * 4096;
    #pragma unroll 4
    for (int i = 0; i < 16; ++i) {
        int i4 = base4 + threadIdx.x + i * 256;
        if (i4 < CE4) {
            int e0 = i4 << 2;
            int c = (e0 >= 3 * E) ? 3 : (e0 >= 2 * E) ? 2 : (e0 >= E) ? 1 : 0;
            int4 rv = rows4[i4];
            atomicAdd(&h[c * NB + (rv.x >> RB_LOG)], 1);
            atomicAdd(&h[c * NB + (rv.y >> RB_LOG)], 1);
            atomicAdd(&h[c * NB + (rv.z >> RB_LOG)], 1);
            atomicAdd(&h[c * NB + (rv.w >> RB_LOG)], 1);
        }
    }
    if (blockIdx.x == 0 && threadIdx.x < (CE & 3)) {
        int e = (CE4 << 2) + threadIdx.x;
        int c = (e >= 3 * E) ? 3 : (e >= 2 * E) ? 2 : (e >= E) ? 1 : 0;
        atomicAdd(&h[c * NB + (rows[e] >> RB_LOG)], 1);
    }
    __syncthreads();
    for (int i = threadIdx.x; i < MB; i += 256)
        if (h[i]) atomicAdd(&bcnt[i], h[i]);
}

// ---- scan bucket counts; also writes the starts[] sentinel ---------------
__global__ __launch_bounds__(1024) void bucket_scan_kernel(const int* __restrict__ bcnt,
                                                           int* __restrict__ bstart,
                                                           int* __restrict__ bhead,
                                                           int* __restrict__ starts,
                                                           int MB, int M) {
    __shared__ int sd[1024];
    int t = threadIdx.x;
    int v = (t < MB) ? bcnt[t] : 0;
    sd[t] = v; __syncthreads();
    for (int off = 1; off < 1024; off <<= 1) {
        int add = (t >= off) ? sd[t - off] : 0;
        __syncthreads();
        sd[t] += add;
        __syncthreads();
    }
    int excl = sd[t] - v;
    if (t < MB) { bstart[t] = excl; bhead[t] = excl; }
    if (t == 1023) starts[M] = sd[1023];   // sentinel = total edge count
}

// ---- partition: 8192 edges/block, 512 threads, 16 edges/thread -----------
// packed: b[0:9) | rank[9:22) | rowlocal[22:32);  b==511 marks invalid
// arena record: x = col | (rowlocal<<17), y = val bits
__global__ __launch_bounds__(512) void partition_kernel(const int* __restrict__ rows,
                                                        const int* __restrict__ cols,
                                                        const float* __restrict__ vals,
                                                        int* __restrict__ bhead,
                                                        int2* __restrict__ arena,
                                                        int CE, int E, int NB, int MB) {
    __shared__ int lcnt[MB_MAX];
    __shared__ int lbase[MB_MAX];
    for (int i = threadIdx.x; i < MB; i += 512) lcnt[i] = 0;
    __syncthreads();
    int base = blockIdx.x * 8192;
    unsigned packed[16];
    #pragma unroll
    for (int i = 0; i < 16; ++i) {
        int e = base + threadIdx.x + i * 512;
        unsigned pk = 511u;
        if (e < CE) {
            int c = (e >= 3 * E) ? 3 : (e >= 2 * E) ? 2 : (e >= E) ? 1 : 0;
            int r = rows[e];
            int b = c * NB + (r >> RB_LOG);
            int rank = atomicAdd(&lcnt[b], 1);   // < 8192 -> 13 bits
            pk = (unsigned)b | ((unsigned)rank << 9) | ((unsigned)(r & (RB - 1)) << 22);
        }
        packed[i] = pk;
    }
    __syncthreads();
    for (int b = threadIdx.x; b < MB; b += 512) {
        int n = lcnt[b];
        lbase[b] = n ? atomicAdd(&bhead[b], n) : 0;
    }
    __syncthreads();
    #pragma unroll
    for (int i = 0; i < 16; ++i) {
        unsigned pk = packed[i];
        int b = pk & 511u;
        if (b != 511) {
            int e    = base + threadIdx.x + i * 512;
            int rank = (pk >> 9) & 8191u;
            int rl   = pk >> 22;
            arena[lbase[b] + rank] = make_int2(cols[e] | (rl << 17), __float_as_int(vals[e]));
        }
    }
}

// ---- in-bucket counting sort by rowlocal (1024 bins); per-row starts -----
__global__ __launch_bounds__(512) void rowsort_kernel(const int* __restrict__ bstart,
                                                      const int* __restrict__ bcnt,
                                                      const int2* __restrict__ src,
                                                      int2* __restrict__ dst,
                                                      int* __restrict__ starts,
                                                      int N, int NB) {
    __shared__ int lcnt[RB];   // 1024 bins
    __shared__ int sd[512];
    int b = blockIdx.x;
    int c = b / NB, rb = b - c * NB;
    int t = threadIdx.x;
    int s = bstart[b], n = bcnt[b];

    int2 recs[STASH];
    #pragma unroll
    for (int k = 0; k < STASH; ++k) {
        int i = t + k * 512;
        if (i < n) recs[k] = src[s + i];
    }
    lcnt[t] = 0; lcnt[t + 512] = 0;
    __syncthreads();
    #pragma unroll
    for (int k = 0; k < STASH; ++k) {
        int i = t + k * 512;
        if (i < n) atomicAdd(&lcnt[(recs[k].x >> 17) & (RB - 1)], 1);
    }
    for (int i = t + STASH * 512; i < n; i += 512)
        atomicAdd(&lcnt[(src[s + i].x >> 17) & (RB - 1)], 1);
    __syncthreads();
    int v0 = lcnt[2 * t], v1 = lcnt[2 * t + 1];
    int ps = v0 + v1;
    sd[t] = ps; __syncthreads();
    for (int off = 1; off < 512; off <<= 1) {
        int add = (t >= off) ? sd[t - off] : 0;
        __syncthreads();
        sd[t] += add;
        __syncthreads();
    }
    int excl = sd[t] - ps;
    int grow = (rb << RB_LOG) + 2 * t;
    if (grow < N)     starts[c * N + grow]     = s + excl;
    if (grow + 1 < N) starts[c * N + grow + 1] = s + excl + v0;
    __syncthreads();
    lcnt[2 * t] = excl; lcnt[2 * t + 1] = excl + v0;   // reuse as heads
    __syncthreads();
    #pragma unroll
    for (int k = 0; k < STASH; ++k) {
        int i = t + k * 512;
        if (i < n) {
            int rl  = (recs[k].x >> 17) & (RB - 1);
            int pos = atomicAdd(&lcnt[rl], 1);
            dst[s + pos] = recs[k];
        }
    }
    // overflow placement (correct: dst is a separate buffer from src)
    for (int i = t + STASH * 512; i < n; i += 512) {
        int2 rec = src[s + i];
        int rl  = (rec.x >> 17) & (RB - 1);
        int pos = atomicAdd(&lcnt[rl], 1);
        dst[s + pos] = rec;
    }
}

// ---- pull: 16-lane group per (class,row); class-major half2 gather -------
__global__ __launch_bounds__(256) void pull2_kernel(const int* __restrict__ starts,
                                                    const int2* __restrict__ arena,
                                                    const __half2* __restrict__ tmp2,
                                                    float* __restrict__ out,
                                                    int N, int M) {
    int p = blockIdx.x * 16 + (threadIdx.x >> 4);
    if (p >= M) return;
    const int lf = threadIdx.x & 15;
    int c   = p / N;
    int row = p - c * N;
    int s = starts[p];
    int n = starts[p + 1] - s;
    const __half2* tc = tmp2 + (size_t)c * N * 16 + lf;   // class-major: row stride 16 half2

    float2 acc = make_float2(0.f, 0.f);
    int base = 0;
    for (; base + 16 <= n; base += 16) {
        int2 r[16];
        #pragma unroll
        for (int j = 0; j < 16; ++j) r[j] = arena[s + base + j];
        #pragma unroll
        for (int j = 0; j < 16; ++j) {
            float  v  = __int_as_float(r[j].y);
            float2 tv = __half22float2(tc[(size_t)(r[j].x & 0x1FFFF) * 16]);
            acc.x = fmaf(v, tv.x, acc.x);
            acc.y = fmaf(v, tv.y, acc.y);
        }
    }
    if (base + 8 <= n) {
        int2 r[8];
        #pragma unroll
        for (int j = 0; j < 8; ++j) r[j] = arena[s + base + j];
        #pragma unroll
        for (int j = 0; j < 8; ++j) {
            float  v  = __int_as_float(r[j].y);
            float2 tv = __half22float2(tc[(size_t)(r[j].x & 0x1FFFF) * 16]);
            acc.x = fmaf(v, tv.x, acc.x);
            acc.y = fmaf(v, tv.y, acc.y);
        }
        base += 8;
    }
    for (; base < n; ++base) {
        int2 rr = arena[s + base];
        float  v  = __int_as_float(rr.y);
        float2 tv = __half22float2(tc[(size_t)(rr.x & 0x1FFFF) * 16]);
        acc.x = fmaf(v, tv.x, acc.x);
        acc.y = fmaf(v, tv.y, acc.y);
    }
    *reinterpret_cast<float2*>(&out[(size_t)row * D_OUT + c * D_C + 2 * lf]) =
        make_float2(fmaxf(acc.x, 0.f), fmaxf(acc.y, 0.f));
}

// ---- fallback: atomic push + relu ----------------------------------------
__global__ __launch_bounds__(256) void scatter_kernel(const int* __restrict__ rows,
                                                      const int* __restrict__ cols,
                                                      const float* __restrict__ vals,
                                                      const __half* __restrict__ tmp,
                                                      float* __restrict__ out,
                                                      long long totalEdges, int E, int N) {
    long long gid = (long long)blockIdx.x * 8 + (threadIdx.x >> 5);
    if (gid >= totalEdges) return;
    const int lane = threadIdx.x & 31;
    const long long e1 = E, e2 = 2LL * E, e3 = 3LL * E;
    int c = (gid >= e3) ? 3 : (gid >= e2) ? 2 : (gid >= e1) ? 1 : 0;
    const float tv = __half2float(tmp[((size_t)c * N + cols[gid]) * 32 + lane]);
    atomicAdd(&out[(size_t)rows[gid] * D_OUT + c * D_C + lane], tv * vals[gid]);
}

__global__ void relu_kernel(float* __restrict__ out, int n4) {
    int i = blockIdx.x * blockDim.x + threadIdx.x;
    if (i < n4) {
        float4 v = reinterpret_cast<float4*>(out)[i];
        v.x = fmaxf(v.x, 0.f); v.y = fmaxf(v.y, 0.f);
        v.z = fmaxf(v.z, 0.f); v.w = fmaxf(v.w, 0.f);
        reinterpret_cast<float4*>(out)[i] = v;
    }
}

extern "C" void kernel_launch(void* const* d_in, const int* in_sizes, int n_in,
                              void* d_out, int out_size, void* d_ws, size_t ws_size,
                              hipStream_t stream) {
    const float* x    = (const float*)d_in[0];
    const float* W    = (const float*)d_in[1];
    const int*   rows = (const int*)d_in[2];
    const int*   cols = (const int*)d_in[3];
    const float* vals = (const float*)d_in[4];
    float* out = (float*)d_out;

    const int N  = in_sizes[0] / D_IN;      // 100000
    const int CE = in_sizes[2];             // 6,400,000
    const int E  = CE / NUM_C;
    const int NB = (N + RB - 1) >> RB_LOG;  // 98
    const int MB = NUM_C * NB;              // 392
    const int M  = NUM_C * N;               // 400,000

    // workspace layout
    size_t off = 0;
    __half* tmp  = (__half*)((char*)d_ws + off); off += (size_t)N * D_OUT * 2;
    off = (off + 15) & ~(size_t)15;
    int* bcnt    = (int*)((char*)d_ws + off);   off += (size_t)MB * 4;
    int* bstart  = (int*)((char*)d_ws + off);   off += (size_t)MB * 4;
    int* bhead   = (int*)((char*)d_ws + off);   off += (size_t)MB * 4;
    int* starts  = (int*)((char*)d_ws + off);   off += (size_t)(M + 1) * 4;
    off = (off + 15) & ~(size_t)15;
    int2* arena  = (int2*)((char*)d_ws + off);  off += (size_t)CE * 8;
    int2* arena2 = (int2*)((char*)d_ws + off);
    size_t off_a = off + (size_t)CE * 8;
    const bool okB = (off   <= ws_size) && (MB <= MB_MAX) && (MB <= 1024);
    const bool okA = (off_a <= ws_size) && (MB <= MB_MAX) && (MB <= 1024);
    int2* sorted = okA ? arena2 : arena;

    const int gemmBlocks = (N + 63) / 64;
    gemm_kernel<<<gemmBlocks, 256, 0, stream>>>(x, W, tmp, N);

    if (okB) {
        hipMemsetAsync(bcnt, 0, (size_t)MB * 4, stream);
        const int histBlocks = ((CE >> 2) + 4095) / 4096;
        bucket_hist_kernel<<<histBlocks, 256, 0, stream>>>(rows, bcnt, CE, E, NB, MB);
        bucket_scan_kernel<<<1, 1024, 0, stream>>>(bcnt, bstart, bhead, starts, MB, M);
        const int partBlocks = (CE + 8191) / 8192;
        partition_kernel<<<partBlocks, 512, 0, stream>>>(rows, cols, vals, bhead, arena, CE, E, NB, MB);
        rowsort_kernel<<<MB, 512, 0, stream>>>(bstart, bcnt, arena, sorted, starts, N, NB);
        const int pullBlocks = (M + 15) / 16;
        pull2_kernel<<<pullBlocks, 256, 0, stream>>>(starts, sorted,
                                                     reinterpret_cast<const __half2*>(tmp), out, N, M);
    } else {
        hipMemsetAsync(d_out, 0, (size_t)out_size * sizeof(float), stream);
        const int scatterBlocks = (CE + 7) / 8;
        scatter_kernel<<<scatterBlocks, 256, 0, stream>>>(rows, cols, vals, tmp, out, (long long)CE, E, N);
        const int n4 = out_size / 4;
        relu_kernel<<<(n4 + 255) / 256, 256, 0, stream>>>(out, n4);
    }
}

// Round 9
// 344.313 us; speedup vs baseline: 4.1732x; 1.0370x over previous
//
#include <hip/hip_runtime.h>
#include <hip/hip_bf16.h>
#include <hip/hip_fp16.h>

// Problem constants: N=100000, D_IN=256, C=4, D_C=32, E=1.6e6
#define D_IN 256
#define D_OUT 128   // C * D_C
#define D_C 32
#define NUM_C 4
#define RB_LOG 10
#define RB 1024         // rows per bucket
#define MB_MAX 400      // bucket-array capacity (NUM_C * ceil(N/RB) = 392)
#define STASH 33        // rowsort stash: 33*512 = 16896 >= max bucket (~16.8k)

typedef _Float16 f16x8 __attribute__((ext_vector_type(8)));
typedef float    f32x4 __attribute__((ext_vector_type(4)));

// ---- W convert+transpose: W[256][128] fp32 -> Wt[128][256] fp16 ----------
__global__ void wcvt_kernel(const float* __restrict__ W, __half* __restrict__ Wt) {
    int t = blockIdx.x * 256 + threadIdx.x;   // 0 .. 32767
    if (t >= D_IN * D_OUT) return;
    int col = t >> 8;     // 0..127
    int k   = t & 255;    // 0..255
    Wt[col * D_IN + k] = __float2half(W[k * D_OUT + col]);
}

// ---- MFMA GEMM: tmp[c][N][32] fp16 = x[N][256] @ W[256][128] -------------
// 64 rows/block, 4 waves; wave w = rows w*16..w*16+15, 8 col-tiles of 16.
// A staged in LDS fp16, slot = kc*64 + (row^kc)  (kc = 16B k-chunk, 0..31).
__global__ __launch_bounds__(256) void gemm_kernel(const float* __restrict__ x,
                                                   const __half* __restrict__ Wt,
                                                   __half* __restrict__ tmp,
                                                   int Nrows) {
    __shared__ f16x8 As[2048];   // 32 KiB: 64 rows x 256 k fp16, swizzled
    const int t    = threadIdx.x;
    const int brow = blockIdx.x * 64;

    // stage x-tile -> fp16 LDS (coalesced fp32 reads, swizzled LDS writes)
    #pragma unroll
    for (int i = 0; i < 8; ++i) {
        int ci  = i * 256 + t;       // 0..2047
        int row = ci >> 5;           // 0..63
        int kc  = ci & 31;           // 16B chunk (8 fp16 = 8 k)
        int grow = brow + row;
        float4 a0 = make_float4(0.f, 0.f, 0.f, 0.f);
        float4 a1 = make_float4(0.f, 0.f, 0.f, 0.f);
        if (grow < Nrows) {
            const float* src = x + (size_t)grow * D_IN + kc * 8;
            a0 = *reinterpret_cast<const float4*>(src);
            a1 = *reinterpret_cast<const float4*>(src + 4);
        }
        f16x8 h;
        h[0] = (_Float16)a0.x; h[1] = (_Float16)a0.y;
        h[2] = (_Float16)a0.z; h[3] = (_Float16)a0.w;
        h[4] = (_Float16)a1.x; h[5] = (_Float16)a1.y;
        h[6] = (_Float16)a1.z; h[7] = (_Float16)a1.w;
        As[kc * 64 + (row ^ kc)] = h;
    }
    __syncthreads();

    const int w   = t >> 6;      // wave 0..3
    const int l   = t & 63;
    const int l15 = l & 15;
    const int hi  = l >> 4;      // 0..3
    const int arow = w * 16 + l15;

    f32x4 acc[8] = {};

    #pragma unroll
    for (int ks = 0; ks < 8; ++ks) {           // K = 256 = 8 x 32
        const int kcA = ks * 4 + hi;
        f16x8 afrag = As[kcA * 64 + (arow ^ kcA)];
        #pragma unroll
        for (int ct = 0; ct < 8; ++ct) {       // 8 col-tiles of 16
            const int col = ct * 16 + l15;
            f16x8 bfrag = *reinterpret_cast<const f16x8*>(
                Wt + (size_t)col * D_IN + ks * 32 + hi * 8);
            acc[ct] = __builtin_amdgcn_mfma_f32_16x16x32_f16(afrag, bfrag, acc[ct], 0, 0, 0);
        }
    }

    // epilogue: D row = (l>>4)*4 + r, col = ct*16 + l15; class-major tmp
    #pragma unroll
    for (int ct = 0; ct < 8; ++ct) {
        const int cls = ct >> 1;
        const int cio = (ct & 1) * 16 + l15;
        #pragma unroll
        for (int r = 0; r < 4; ++r) {
            int grow = brow + w * 16 + hi * 4 + r;
            if (grow < Nrows)
                tmp[((size_t)cls * Nrows + grow) * 32 + cio] = __float2half((float)acc[ct][r]);
        }
    }
}

// ---- bucket histogram (LDS-aggregated, int4 loads) -----------------------
__global__ __launch_bounds__(256) void bucket_hist_kernel(const int* __restrict__ rows,
                                                          int* __restrict__ bcnt,
                                                          int CE, int E, int NB, int MB) {
    __shared__ int h[MB_MAX];
    for (int i = threadIdx.x; i < MB; i += 256) h[i] = 0;
    __syncthreads();
    const int CE4 = CE >> 2;
    const int4* rows4 = reinterpret_cast<const int4*>(rows);
    int base4 = blockIdx.x * 4096;
    #pragma unroll 4
    for (int i = 0; i < 16; ++i) {
        int i4 = base4 + threadIdx.x + i * 256;
        if (i4 < CE4) {
            int e0 = i4 << 2;
            int c = (e0 >= 3 * E) ? 3 : (e0 >= 2 * E) ? 2 : (e0 >= E) ? 1 : 0;
            int4 rv = rows4[i4];
            atomicAdd(&h[c * NB + (rv.x >> RB_LOG)], 1);
            atomicAdd(&h[c * NB + (rv.y >> RB_LOG)], 1);
            atomicAdd(&h[c * NB + (rv.z >> RB_LOG)], 1);
            atomicAdd(&h[c * NB + (rv.w >> RB_LOG)], 1);
        }
    }
    if (blockIdx.x == 0 && threadIdx.x < (CE & 3)) {
        int e = (CE4 << 2) + threadIdx.x;
        int c = (e >= 3 * E) ? 3 : (e >= 2 * E) ? 2 : (e >= E) ? 1 : 0;
        atomicAdd(&h[c * NB + (rows[e] >> RB_LOG)], 1);
    }
    __syncthreads();
    for (int i = threadIdx.x; i < MB; i += 256)
        if (h[i]) atomicAdd(&bcnt[i], h[i]);
}

// ---- scan bucket counts; also writes the starts[] sentinel ---------------
__global__ __launch_bounds__(1024) void bucket_scan_kernel(const int* __restrict__ bcnt,
                                                           int* __restrict__ bstart,
                                                           int* __restrict__ bhead,
                                                           int* __restrict__ starts,
                                                           int MB, int M) {
    __shared__ int sd[1024];
    int t = threadIdx.x;
    int v = (t < MB) ? bcnt[t] : 0;
    sd[t] = v; __syncthreads();
    for (int off = 1; off < 1024; off <<= 1) {
        int add = (t >= off) ? sd[t - off] : 0;
        __syncthreads();
        sd[t] += add;
        __syncthreads();
    }
    int excl = sd[t] - v;
    if (t < MB) { bstart[t] = excl; bhead[t] = excl; }
    if (t == 1023) starts[M] = sd[1023];   // sentinel = total edge count
}

// ---- partition: 8192 edges/block, 512 threads, 16 edges/thread -----------
// packed: b[0:9) | rank[9:22) | rowlocal[22:32);  b==511 marks invalid
// arena record: x = col | (rowlocal<<17), y = val bits
__global__ __launch_bounds__(512) void partition_kernel(const int* __restrict__ rows,
                                                        const int* __restrict__ cols,
                                                        const float* __restrict__ vals,
                                                        int* __restrict__ bhead,
                                                        int2* __restrict__ arena,
                                                        int CE, int E, int NB, int MB) {
    __shared__ int lcnt[MB_MAX];
    __shared__ int lbase[MB_MAX];
    for (int i = threadIdx.x; i < MB; i += 512) lcnt[i] = 0;
    __syncthreads();
    int base = blockIdx.x * 8192;
    unsigned packed[16];
    #pragma unroll
    for (int i = 0; i < 16; ++i) {
        int e = base + threadIdx.x + i * 512;
        unsigned pk = 511u;
        if (e < CE) {
            int c = (e >= 3 * E) ? 3 : (e >= 2 * E) ? 2 : (e >= E) ? 1 : 0;
            int r = rows[e];
            int b = c * NB + (r >> RB_LOG);
            int rank = atomicAdd(&lcnt[b], 1);   // < 8192 -> 13 bits
            pk = (unsigned)b | ((unsigned)rank << 9) | ((unsigned)(r & (RB - 1)) << 22);
        }
        packed[i] = pk;
    }
    __syncthreads();
    for (int b = threadIdx.x; b < MB; b += 512) {
        int n = lcnt[b];
        lbase[b] = n ? atomicAdd(&bhead[b], n) : 0;
    }
    __syncthreads();
    #pragma unroll
    for (int i = 0; i < 16; ++i) {
        unsigned pk = packed[i];
        int b = pk & 511u;
        if (b != 511) {
            int e    = base + threadIdx.x + i * 512;
            int rank = (pk >> 9) & 8191u;
            int rl   = pk >> 22;
            arena[lbase[b] + rank] = make_int2(cols[e] | (rl << 17), __float_as_int(vals[e]));
        }
    }
}

// ---- in-bucket counting sort by rowlocal (1024 bins); per-row starts -----
__global__ __launch_bounds__(512) void rowsort_kernel(const int* __restrict__ bstart,
                                                      const int* __restrict__ bcnt,
                                                      const int2* __restrict__ src,
                                                      int2* __restrict__ dst,
                                                      int* __restrict__ starts,
                                                      int N, int NB) {
    __shared__ int lcnt[RB];   // 1024 bins
    __shared__ int sd[512];
    int b = blockIdx.x;
    int c = b / NB, rb = b - c * NB;
    int t = threadIdx.x;
    int s = bstart[b], n = bcnt[b];

    int2 recs[STASH];
    #pragma unroll
    for (int k = 0; k < STASH; ++k) {
        int i = t + k * 512;
        if (i < n) recs[k] = src[s + i];
    }
    lcnt[t] = 0; lcnt[t + 512] = 0;
    __syncthreads();
    #pragma unroll
    for (int k = 0; k < STASH; ++k) {
        int i = t + k * 512;
        if (i < n) atomicAdd(&lcnt[(recs[k].x >> 17) & (RB - 1)], 1);
    }
    for (int i = t + STASH * 512; i < n; i += 512)
        atomicAdd(&lcnt[(src[s + i].x >> 17) & (RB - 1)], 1);
    __syncthreads();
    int v0 = lcnt[2 * t], v1 = lcnt[2 * t + 1];
    int ps = v0 + v1;
    sd[t] = ps; __syncthreads();
    for (int off = 1; off < 512; off <<= 1) {
        int add = (t >= off) ? sd[t - off] : 0;
        __syncthreads();
        sd[t] += add;
        __syncthreads();
    }
    int excl = sd[t] - ps;
    int grow = (rb << RB_LOG) + 2 * t;
    if (grow < N)     starts[c * N + grow]     = s + excl;
    if (grow + 1 < N) starts[c * N + grow + 1] = s + excl + v0;
    __syncthreads();
    lcnt[2 * t] = excl; lcnt[2 * t + 1] = excl + v0;   // reuse as heads
    __syncthreads();
    #pragma unroll
    for (int k = 0; k < STASH; ++k) {
        int i = t + k * 512;
        if (i < n) {
            int rl  = (recs[k].x >> 17) & (RB - 1);
            int pos = atomicAdd(&lcnt[rl], 1);
            dst[s + pos] = recs[k];
        }
    }
    // overflow placement (correct: dst is a separate buffer from src)
    for (int i = t + STASH * 512; i < n; i += 512) {
        int2 rec = src[s + i];
        int rl  = (rec.x >> 17) & (RB - 1);
        int pos = atomicAdd(&lcnt[rl], 1);
        dst[s + pos] = rec;
    }
}

// ---- pull: 16-lane group per (class,row); class-major half2 gather -------
__global__ __launch_bounds__(256) void pull2_kernel(const int* __restrict__ starts,
                                                    const int2* __restrict__ arena,
                                                    const __half2* __restrict__ tmp2,
                                                    float* __restrict__ out,
                                                    int N, int M) {
    int p = blockIdx.x * 16 + (threadIdx.x >> 4);
    if (p >= M) return;
    const int lf = threadIdx.x & 15;
    int c   = p / N;
    int row = p - c * N;
    int s = starts[p];
    int n = starts[p + 1] - s;
    const __half2* tc = tmp2 + (size_t)c * N * 16 + lf;   // class-major: row stride 16 half2

    float2 acc = make_float2(0.f, 0.f);
    int base = 0;
    for (; base + 16 <= n; base += 16) {
        int2 r[16];
        #pragma unroll
        for (int j = 0; j < 16; ++j) r[j] = arena[s + base + j];
        #pragma unroll
        for (int j = 0; j < 16; ++j) {
            float  v  = __int_as_float(r[j].y);
            float2 tv = __half22float2(tc[(size_t)(r[j].x & 0x1FFFF) * 16]);
            acc.x = fmaf(v, tv.x, acc.x);
            acc.y = fmaf(v, tv.y, acc.y);
        }
    }
    if (base + 8 <= n) {
        int2 r[8];
        #pragma unroll
        for (int j = 0; j < 8; ++j) r[j] = arena[s + base + j];
        #pragma unroll
        for (int j = 0; j < 8; ++j) {
            float  v  = __int_as_float(r[j].y);
            float2 tv = __half22float2(tc[(size_t)(r[j].x & 0x1FFFF) * 16]);
            acc.x = fmaf(v, tv.x, acc.x);
            acc.y = fmaf(v, tv.y, acc.y);
        }
        base += 8;
    }
    for (; base < n; ++base) {
        int2 rr = arena[s + base];
        float  v  = __int_as_float(rr.y);
        float2 tv = __half22float2(tc[(size_t)(rr.x & 0x1FFFF) * 16]);
        acc.x = fmaf(v, tv.x, acc.x);
        acc.y = fmaf(v, tv.y, acc.y);
    }
    *reinterpret_cast<float2*>(&out[(size_t)row * D_OUT + c * D_C + 2 * lf]) =
        make_float2(fmaxf(acc.x, 0.f), fmaxf(acc.y, 0.f));
}

// ---- fallback: atomic push + relu ----------------------------------------
__global__ __launch_bounds__(256) void scatter_kernel(const int* __restrict__ rows,
                                                      const int* __restrict__ cols,
                                                      const float* __restrict__ vals,
                                                      const __half* __restrict__ tmp,
                                                      float* __restrict__ out,
                                                      long long totalEdges, int E, int N) {
    long long gid = (long long)blockIdx.x * 8 + (threadIdx.x >> 5);
    if (gid >= totalEdges) return;
    const int lane = threadIdx.x & 31;
    const long long e1 = E, e2 = 2LL * E, e3 = 3LL * E;
    int c = (gid >= e3) ? 3 : (gid >= e2) ? 2 : (gid >= e1) ? 1 : 0;
    const float tv = __half2float(tmp[((size_t)c * N + cols[gid]) * 32 + lane]);
    atomicAdd(&out[(size_t)rows[gid] * D_OUT + c * D_C + lane], tv * vals[gid]);
}

__global__ void relu_kernel(float* __restrict__ out, int n4) {
    int i = blockIdx.x * blockDim.x + threadIdx.x;
    if (i < n4) {
        float4 v = reinterpret_cast<float4*>(out)[i];
        v.x = fmaxf(v.x, 0.f); v.y = fmaxf(v.y, 0.f);
        v.z = fmaxf(v.z, 0.f); v.w = fmaxf(v.w, 0.f);
        reinterpret_cast<float4*>(out)[i] = v;
    }
}

extern "C" void kernel_launch(void* const* d_in, const int* in_sizes, int n_in,
                              void* d_out, int out_size, void* d_ws, size_t ws_size,
                              hipStream_t stream) {
    const float* x    = (const float*)d_in[0];
    const float* W    = (const float*)d_in[1];
    const int*   rows = (const int*)d_in[2];
    const int*   cols = (const int*)d_in[3];
    const float* vals = (const float*)d_in[4];
    float* out = (float*)d_out;

    const int N  = in_sizes[0] / D_IN;      // 100000
    const int CE = in_sizes[2];             // 6,400,000
    const int E  = CE / NUM_C;
    const int NB = (N + RB - 1) >> RB_LOG;  // 98
    const int MB = NUM_C * NB;              // 392
    const int M  = NUM_C * N;               // 400,000

    // workspace layout
    size_t off = 0;
    __half* tmp  = (__half*)((char*)d_ws + off); off += (size_t)N * D_OUT * 2;
    off = (off + 15) & ~(size_t)15;
    __half* Wt   = (__half*)((char*)d_ws + off); off += (size_t)D_IN * D_OUT * 2;
    int* bcnt    = (int*)((char*)d_ws + off);   off += (size_t)MB * 4;
    int* bstart  = (int*)((char*)d_ws + off);   off += (size_t)MB * 4;
    int* bhead   = (int*)((char*)d_ws + off);   off += (size_t)MB * 4;
    int* starts  = (int*)((char*)d_ws + off);   off += (size_t)(M + 1) * 4;
    off = (off + 15) & ~(size_t)15;
    int2* arena  = (int2*)((char*)d_ws + off);  off += (size_t)CE * 8;
    int2* arena2 = (int2*)((char*)d_ws + off);
    size_t off_a = off + (size_t)CE * 8;
    const bool okB = (off   <= ws_size) && (MB <= MB_MAX) && (MB <= 1024);
    const bool okA = (off_a <= ws_size) && (MB <= MB_MAX) && (MB <= 1024);
    int2* sorted = okA ? arena2 : arena;

    wcvt_kernel<<<(D_IN * D_OUT + 255) / 256, 256, 0, stream>>>(W, Wt);
    const int gemmBlocks = (N + 63) / 64;
    gemm_kernel<<<gemmBlocks, 256, 0, stream>>>(x, Wt, tmp, N);

    if (okB) {
        hipMemsetAsync(bcnt, 0, (size_t)MB * 4, stream);
        const int histBlocks = ((CE >> 2) + 4095) / 4096;
        bucket_hist_kernel<<<histBlocks, 256, 0, stream>>>(rows, bcnt, CE, E, NB, MB);
        bucket_scan_kernel<<<1, 1024, 0, stream>>>(bcnt, bstart, bhead, starts, MB, M);
        const int partBlocks = (CE + 8191) / 8192;
        partition_kernel<<<partBlocks, 512, 0, stream>>>(rows, cols, vals, bhead, arena, CE, E, NB, MB);
        rowsort_kernel<<<MB, 512, 0, stream>>>(bstart, bcnt, arena, sorted, starts, N, NB);
        const int pullBlocks = (M + 15) / 16;
        pull2_kernel<<<pullBlocks, 256, 0, stream>>>(starts, sorted,
                                                     reinterpret_cast<const __half2*>(tmp), out, N, M);
    } else {
        hipMemsetAsync(d_out, 0, (size_t)out_size * sizeof(float), stream);
        const int scatterBlocks = (CE + 7) / 8;
        scatter_kernel<<<scatterBlocks, 256, 0, stream>>>(rows, cols, vals, tmp, out, (long long)CE, E, N);
        const int n4 = out_size / 4;
        relu_kernel<<<(n4 + 255) / 256, 256, 0, stream>>>(out, n4);
    }
}